// Round 3
// baseline (353.426 us; speedup 1.0000x reference)
//
#include <hip/hip_runtime.h>

#define N_NODES 50000
#define IN_DIM  128
#define OUT_DIM 256
#define N_EDGES 800000
#define EDGE_BLOCKS 3125   // N_EDGES/256
#define CONV_BLOCKS 3125   // (N_NODES*IN_DIM/8)/256

typedef short bf16x8 __attribute__((ext_vector_type(8)));   // 8 bf16 = 4 VGPRs
typedef float f32x4  __attribute__((ext_vector_type(4)));   // MFMA acc
typedef unsigned short ushort8_t __attribute__((ext_vector_type(8)));

__device__ __forceinline__ unsigned short f2bf(float f) {
    unsigned u = __float_as_uint(f);
    return (unsigned short)((u + 0x7fffu + ((u >> 16) & 1u)) >> 16);
}
__device__ __forceinline__ float bf2f(unsigned short h) {
    return __uint_as_float(((unsigned)h) << 16);
}

// ---------------- prep: histogram of dst + x -> bf16 convert (fused) ----------------

__global__ __launch_bounds__(256) void k_prep(const int* __restrict__ ei,
                                              int* __restrict__ counts,
                                              const float* __restrict__ x,
                                              unsigned short* __restrict__ xb) {
    int b = blockIdx.x;
    if (b < EDGE_BLOCKS) {
        int e = b * 256 + threadIdx.x;
        if (e < N_EDGES) {
            int d = ei[2 * e + 1];
            atomicAdd(&counts[d], 1);
        }
    } else {
        int t = (b - EDGE_BLOCKS) * 256 + threadIdx.x;
        int base = t * 8;                      // 800K threads x 8 elems = 6.4M
        float4 a = *(const float4*)&x[base];
        float4 c = *(const float4*)&x[base + 4];
        ushort8_t o;
        o[0] = f2bf(a.x); o[1] = f2bf(a.y); o[2] = f2bf(a.z); o[3] = f2bf(a.w);
        o[4] = f2bf(c.x); o[5] = f2bf(c.y); o[6] = f2bf(c.z); o[7] = f2bf(c.w);
        *(ushort8_t*)&xb[base] = o;
    }
}

// ---------------- single-block scan: counts -> exclusive ptr + dinv ----------------

__global__ __launch_bounds__(1024) void k_scan(const int* __restrict__ counts,
                                               int* __restrict__ ptr,
                                               float* __restrict__ dinv) {
    __shared__ int psum[1024];
    int t = threadIdx.x;
    const int PER = 49;                        // 1024*49 = 50176 >= 50000
    int base = t * PER;
    int local = 0;
    for (int j = 0; j < PER; ++j) {
        int i = base + j;
        if (i < N_NODES) local += counts[i];
    }
    psum[t] = local;
    __syncthreads();
    for (int off = 1; off < 1024; off <<= 1) {
        int v = (t >= off) ? psum[t - off] : 0;
        __syncthreads();
        psum[t] += v;
        __syncthreads();
    }
    int run = (t == 0) ? 0 : psum[t - 1];      // exclusive prefix of this range
    for (int j = 0; j < PER; ++j) {
        int i = base + j;
        if (i < N_NODES) {
            int c = counts[i];
            ptr[i] = run;                      // exclusive start (cursor)
            dinv[i] = rsqrtf((float)(c + 1));  // +1 self-loop
            run += c;
        }
    }
}

__global__ void k_scatter(const int* __restrict__ ei, int* __restrict__ ptr,
                          int* __restrict__ srcl) {
    int e = blockIdx.x * 256 + threadIdx.x;
    if (e < N_EDGES) {
        int s = ei[2 * e];
        int d = ei[2 * e + 1];
        int pos = atomicAdd(&ptr[d], 1);       // after: ptr[d] == end
        srcl[pos] = s;
    }
}

// -------- aggregation: y[i] = dinv[i]*(dinv[i]*x[i] + sum_s dinv[s]*x[s]) --------
// wave-per-node, bf16 x gather (1 dword = 2 cols per lane), shfl-broadcast, 8x batch.

__device__ __forceinline__ float blo(unsigned p) { return __uint_as_float(p << 16); }
__device__ __forceinline__ float bhi(unsigned p) { return __uint_as_float(p & 0xffff0000u); }

__global__ __launch_bounds__(256) void k_aggregate(
        const unsigned* __restrict__ xbu, const float* __restrict__ dinv,
        const int* __restrict__ ptr, const int* __restrict__ counts,
        const int* __restrict__ srcl, float* __restrict__ y) {
    int wv = threadIdx.x >> 6;
    int lane = threadIdx.x & 63;
    int i = blockIdx.x * 4 + wv;
    if (i >= N_NODES) return;
    float di = dinv[i];
    int end = ptr[i];
    int start = end - counts[i];
    unsigned pself = xbu[i * 64 + lane];
    float sx = di * blo(pself), sy = di * bhi(pself);     // self-loop term
    for (int e0 = start; e0 < end; e0 += 64) {
        int ne = end - e0; if (ne > 64) ne = 64;
        int s = 0; float w = 0.f;
        if (lane < ne) {
            s = srcl[e0 + lane];
            w = dinv[s];
        }
        int t = 0;
        for (; t + 8 <= ne; t += 8) {
            int s0 = __shfl(s, t),     s1 = __shfl(s, t + 1);
            int s2 = __shfl(s, t + 2), s3 = __shfl(s, t + 3);
            int s4 = __shfl(s, t + 4), s5 = __shfl(s, t + 5);
            int s6 = __shfl(s, t + 6), s7 = __shfl(s, t + 7);
            float w0 = __shfl(w, t),     w1 = __shfl(w, t + 1);
            float w2 = __shfl(w, t + 2), w3 = __shfl(w, t + 3);
            float w4 = __shfl(w, t + 4), w5 = __shfl(w, t + 5);
            float w6 = __shfl(w, t + 6), w7 = __shfl(w, t + 7);
            unsigned p0 = xbu[s0 * 64 + lane], p1 = xbu[s1 * 64 + lane];
            unsigned p2 = xbu[s2 * 64 + lane], p3 = xbu[s3 * 64 + lane];
            unsigned p4 = xbu[s4 * 64 + lane], p5 = xbu[s5 * 64 + lane];
            unsigned p6 = xbu[s6 * 64 + lane], p7 = xbu[s7 * 64 + lane];
            sx += w0 * blo(p0) + w1 * blo(p1) + w2 * blo(p2) + w3 * blo(p3)
                + w4 * blo(p4) + w5 * blo(p5) + w6 * blo(p6) + w7 * blo(p7);
            sy += w0 * bhi(p0) + w1 * bhi(p1) + w2 * bhi(p2) + w3 * bhi(p3)
                + w4 * bhi(p4) + w5 * bhi(p5) + w6 * bhi(p6) + w7 * bhi(p7);
        }
        for (; t < ne; ++t) {
            int st = __shfl(s, t); float wt = __shfl(w, t);
            unsigned p = xbu[st * 64 + lane];
            sx += wt * blo(p); sy += wt * bhi(p);
        }
    }
    float2 o; o.x = di * sx; o.y = di * sy;
    ((float2*)y)[i * 64 + lane] = o;
}

// ---------------- GEMM: out = relu(y @ W^T + b) via split-bf16 MFMA ----------------

#define BM 64
#define BN 64
#define BK 64
#define LDK 72   // padded K-stride (bf16 elems): 144B rows -> 16B aligned, 2-way banks (free)

__global__ __launch_bounds__(256) void k_gemm(
        const float* __restrict__ y, const float* __restrict__ W,
        const float* __restrict__ bias, float* __restrict__ out) {
    __shared__ unsigned short Ah[BM * LDK], Al[BM * LDK];
    __shared__ unsigned short Bh[BN * LDK], Bl[BN * LDK];
    int tid = threadIdx.x;
    int lane = tid & 63;
    int wv = tid >> 6;
    int jb = blockIdx.x * BN;        // n-block fastest-varying -> y-tile L2 reuse
    int i0 = blockIdx.y * BM;
    int n0 = wv * 16;
    int rl = lane & 15;              // m (A) / n (B) row within 16-tile
    int quad = lane >> 4;

    f32x4 acc[4] = {{0.f,0.f,0.f,0.f},{0.f,0.f,0.f,0.f},{0.f,0.f,0.f,0.f},{0.f,0.f,0.f,0.f}};

    for (int kc = 0; kc < IN_DIM; kc += BK) {
        __syncthreads();
        #pragma unroll
        for (int it = 0; it < 4; ++it) {
            int g = it * 256 + tid;          // 0..1023
            int r = g >> 4;                  // 0..63
            int c4 = g & 15;                 // float4 index along k
            int row = i0 + r; if (row >= N_NODES) row = N_NODES - 1;
            float4 v = *(const float4*)&y[row * IN_DIM + kc + c4 * 4];
            float4 wv4 = *(const float4*)&W[(jb + r) * IN_DIM + kc + c4 * 4];
            int a = r * LDK + c4 * 4;
            {
                unsigned short h0 = f2bf(v.x), h1 = f2bf(v.y), h2 = f2bf(v.z), h3 = f2bf(v.w);
                *(ushort4*)&Ah[a] = make_ushort4(h0, h1, h2, h3);
                *(ushort4*)&Al[a] = make_ushort4(
                    f2bf(v.x - bf2f(h0)), f2bf(v.y - bf2f(h1)),
                    f2bf(v.z - bf2f(h2)), f2bf(v.w - bf2f(h3)));
            }
            {
                unsigned short h0 = f2bf(wv4.x), h1 = f2bf(wv4.y), h2 = f2bf(wv4.z), h3 = f2bf(wv4.w);
                *(ushort4*)&Bh[a] = make_ushort4(h0, h1, h2, h3);
                *(ushort4*)&Bl[a] = make_ushort4(
                    f2bf(wv4.x - bf2f(h0)), f2bf(wv4.y - bf2f(h1)),
                    f2bf(wv4.z - bf2f(h2)), f2bf(wv4.w - bf2f(h3)));
            }
        }
        __syncthreads();
        #pragma unroll
        for (int ks = 0; ks < 2; ++ks) {
            int koff = ks * 32 + quad * 8;
            bf16x8 bh = *(bf16x8*)&Bh[(n0 + rl) * LDK + koff];
            bf16x8 bl = *(bf16x8*)&Bl[(n0 + rl) * LDK + koff];
            #pragma unroll
            for (int mt = 0; mt < 4; ++mt) {
                bf16x8 ah = *(bf16x8*)&Ah[(mt * 16 + rl) * LDK + koff];
                bf16x8 al = *(bf16x8*)&Al[(mt * 16 + rl) * LDK + koff];
                acc[mt] = __builtin_amdgcn_mfma_f32_16x16x32_bf16(ah, bh, acc[mt], 0, 0, 0);
                acc[mt] = __builtin_amdgcn_mfma_f32_16x16x32_bf16(ah, bl, acc[mt], 0, 0, 0);
                acc[mt] = __builtin_amdgcn_mfma_f32_16x16x32_bf16(al, bh, acc[mt], 0, 0, 0);
            }
        }
    }

    float bv = bias[jb + n0 + rl];
    #pragma unroll
    for (int mt = 0; mt < 4; ++mt) {
        #pragma unroll
        for (int r = 0; r < 4; ++r) {
            int row = i0 + mt * 16 + quad * 4 + r;
            if (row < N_NODES) {
                float v = acc[mt][r] + bv;
                out[row * OUT_DIM + jb + n0 + rl] = fmaxf(v, 0.f);
            }
        }
    }
}

// ---------------- launch ----------------

extern "C" void kernel_launch(void* const* d_in, const int* in_sizes, int n_in,
                              void* d_out, int out_size, void* d_ws, size_t ws_size,
                              hipStream_t stream) {
    const float* x  = (const float*)d_in[0];
    const int*   ei = (const int*)d_in[1];
    const float* W  = (const float*)d_in[2];
    const float* b  = (const float*)d_in[3];
    float* out = (float*)d_out;

    char* ws = (char*)d_ws;
    int*            counts = (int*)(ws + 0);          //  50000 ints
    int*            ptr    = (int*)(ws + 200704);     //  50000 ints
    float*          dinv   = (float*)(ws + 401664);   //  50000 floats
    int*            srcl   = (int*)(ws + 602368);     //  800000 ints
    float*          y      = (float*)(ws + 3802368);  //  6400000 floats
    unsigned short* xb     = (unsigned short*)(ws + 29402368); // 6400000 bf16 (12.8MB)

    hipMemsetAsync(counts, 0, N_NODES * sizeof(int), stream);

    k_prep<<<EDGE_BLOCKS + CONV_BLOCKS, 256, 0, stream>>>(ei, counts, x, xb);
    k_scan<<<1, 1024, 0, stream>>>(counts, ptr, dinv);
    k_scatter<<<EDGE_BLOCKS, 256, 0, stream>>>(ei, ptr, srcl);
    k_aggregate<<<(N_NODES + 3) / 4, 256, 0, stream>>>((const unsigned*)xb, dinv, ptr,
                                                       counts, srcl, y);
    dim3 g(OUT_DIM / BN, (N_NODES + BM - 1) / BM);   // n fastest -> y-tile reuse in L2
    k_gemm<<<g, 256, 0, stream>>>(y, W, b, out);
}

// Round 4
// 236.856 us; speedup vs baseline: 1.4922x; 1.4922x over previous
//
#include <hip/hip_runtime.h>

#define N_NODES 50000
#define IN_DIM  128
#define OUT_DIM 256
#define N_EDGES 800000
#define EDGE_BLOCKS 3125   // N_EDGES/256
#define CONV_BLOCKS 3125   // (N_NODES*IN_DIM/8)/256
#define WCONV_BLOCKS 16    // (OUT_DIM*IN_DIM/8)/256
#define SCAN_BLOCKS 49     // ceil(50000/1024)

typedef short bf16x8 __attribute__((ext_vector_type(8)));   // 8 bf16 = 4 VGPRs
typedef float f32x4  __attribute__((ext_vector_type(4)));   // MFMA acc
typedef unsigned short ushort8_t __attribute__((ext_vector_type(8)));

__device__ __forceinline__ unsigned short f2bf(float f) {
    unsigned u = __float_as_uint(f);
    return (unsigned short)((u + 0x7fffu + ((u >> 16) & 1u)) >> 16);
}
__device__ __forceinline__ float bf2f(unsigned short h) {
    return __uint_as_float(((unsigned)h) << 16);
}

// ---- prep: dst histogram + x->bf16 convert + W->split-bf16 convert (fused grid) ----

__global__ __launch_bounds__(256) void k_prep(const int* __restrict__ ei,
                                              int* __restrict__ counts,
                                              const float* __restrict__ x,
                                              unsigned short* __restrict__ xb,
                                              const float* __restrict__ W,
                                              unsigned short* __restrict__ Wh,
                                              unsigned short* __restrict__ Wl) {
    int b = blockIdx.x;
    if (b < EDGE_BLOCKS) {
        int e = b * 256 + threadIdx.x;
        if (e < N_EDGES) {
            int d = ei[2 * e + 1];
            atomicAdd(&counts[d], 1);
        }
    } else if (b < EDGE_BLOCKS + CONV_BLOCKS) {
        int t = (b - EDGE_BLOCKS) * 256 + threadIdx.x;
        int base = t * 8;
        float4 a = *(const float4*)&x[base];
        float4 c = *(const float4*)&x[base + 4];
        ushort8_t o;
        o[0] = f2bf(a.x); o[1] = f2bf(a.y); o[2] = f2bf(a.z); o[3] = f2bf(a.w);
        o[4] = f2bf(c.x); o[5] = f2bf(c.y); o[6] = f2bf(c.z); o[7] = f2bf(c.w);
        *(ushort8_t*)&xb[base] = o;
    } else {
        int t = (b - EDGE_BLOCKS - CONV_BLOCKS) * 256 + threadIdx.x;
        int base = t * 8;
        float4 a = *(const float4*)&W[base];
        float4 c = *(const float4*)&W[base + 4];
        ushort8_t h, l;
        h[0] = f2bf(a.x); h[1] = f2bf(a.y); h[2] = f2bf(a.z); h[3] = f2bf(a.w);
        h[4] = f2bf(c.x); h[5] = f2bf(c.y); h[6] = f2bf(c.z); h[7] = f2bf(c.w);
        l[0] = f2bf(a.x - bf2f(h[0])); l[1] = f2bf(a.y - bf2f(h[1]));
        l[2] = f2bf(a.z - bf2f(h[2])); l[3] = f2bf(a.w - bf2f(h[3]));
        l[4] = f2bf(c.x - bf2f(h[4])); l[5] = f2bf(c.y - bf2f(h[5]));
        l[6] = f2bf(c.z - bf2f(h[6])); l[7] = f2bf(c.w - bf2f(h[7]));
        *(ushort8_t*)&Wh[base] = h;
        *(ushort8_t*)&Wl[base] = l;
    }
}

// ---------------- parallel scan: 49 blocks + finalize folds block-sum prefix ----------------

__global__ __launch_bounds__(1024) void k_scan1(const int* __restrict__ counts,
                                                int* __restrict__ ptr,
                                                int* __restrict__ bsum) {
    __shared__ int lds[1024];
    int i = blockIdx.x * 1024 + threadIdx.x;
    int v = (i < N_NODES) ? counts[i] : 0;
    lds[threadIdx.x] = v;
    __syncthreads();
    for (int off = 1; off < 1024; off <<= 1) {
        int t = (threadIdx.x >= off) ? lds[threadIdx.x - off] : 0;
        __syncthreads();
        lds[threadIdx.x] += t;
        __syncthreads();
    }
    if (i < N_NODES) ptr[i] = lds[threadIdx.x];       // inclusive within block
    if (threadIdx.x == 1023) bsum[blockIdx.x] = lds[1023];
}

__global__ __launch_bounds__(256) void k_finalize(int* __restrict__ ptr,
                                                  const int* __restrict__ counts,
                                                  const int* __restrict__ bsum,
                                                  float* __restrict__ dinv) {
    int i = blockIdx.x * 256 + threadIdx.x;
    if (i < N_NODES) {
        int blk = i >> 10;
        int off = 0;
        for (int b = 0; b < blk; ++b) off += bsum[b];  // <=48 L2-broadcast reads
        int incl = ptr[i] + off;
        ptr[i] = incl - counts[i];                     // exclusive start (cursor)
        dinv[i] = rsqrtf((float)(counts[i] + 1));      // +1 self-loop
    }
}

__global__ void k_scatter(const int* __restrict__ ei, int* __restrict__ ptr,
                          int* __restrict__ srcl) {
    int e = blockIdx.x * 256 + threadIdx.x;
    if (e < N_EDGES) {
        int s = ei[2 * e];
        int d = ei[2 * e + 1];
        int pos = atomicAdd(&ptr[d], 1);       // after: ptr[d] == end
        srcl[pos] = s;
    }
}

// -------- aggregation: y[i] = dinv[i]*(dinv[i]*x[i] + sum_s dinv[s]*x[s]) --------
// wave-per-node, bf16 gather, shfl-broadcast, 8x batch; writes split-bf16 yh/yl.

__device__ __forceinline__ float blo(unsigned p) { return __uint_as_float(p << 16); }
__device__ __forceinline__ float bhi(unsigned p) { return __uint_as_float(p & 0xffff0000u); }

__global__ __launch_bounds__(256) void k_aggregate(
        const unsigned* __restrict__ xbu, const float* __restrict__ dinv,
        const int* __restrict__ ptr, const int* __restrict__ counts,
        const int* __restrict__ srcl,
        unsigned* __restrict__ yh, unsigned* __restrict__ yl) {
    int wv = threadIdx.x >> 6;
    int lane = threadIdx.x & 63;
    int i = blockIdx.x * 4 + wv;
    if (i >= N_NODES) return;
    float di = dinv[i];
    int end = ptr[i];
    int start = end - counts[i];
    unsigned pself = xbu[i * 64 + lane];
    float sx = di * blo(pself), sy = di * bhi(pself);     // self-loop term
    for (int e0 = start; e0 < end; e0 += 64) {
        int ne = end - e0; if (ne > 64) ne = 64;
        int s = 0; float w = 0.f;
        if (lane < ne) {
            s = srcl[e0 + lane];
            w = dinv[s];
        }
        int t = 0;
        for (; t + 8 <= ne; t += 8) {
            int s0 = __shfl(s, t),     s1 = __shfl(s, t + 1);
            int s2 = __shfl(s, t + 2), s3 = __shfl(s, t + 3);
            int s4 = __shfl(s, t + 4), s5 = __shfl(s, t + 5);
            int s6 = __shfl(s, t + 6), s7 = __shfl(s, t + 7);
            float w0 = __shfl(w, t),     w1 = __shfl(w, t + 1);
            float w2 = __shfl(w, t + 2), w3 = __shfl(w, t + 3);
            float w4 = __shfl(w, t + 4), w5 = __shfl(w, t + 5);
            float w6 = __shfl(w, t + 6), w7 = __shfl(w, t + 7);
            unsigned p0 = xbu[s0 * 64 + lane], p1 = xbu[s1 * 64 + lane];
            unsigned p2 = xbu[s2 * 64 + lane], p3 = xbu[s3 * 64 + lane];
            unsigned p4 = xbu[s4 * 64 + lane], p5 = xbu[s5 * 64 + lane];
            unsigned p6 = xbu[s6 * 64 + lane], p7 = xbu[s7 * 64 + lane];
            sx += w0 * blo(p0) + w1 * blo(p1) + w2 * blo(p2) + w3 * blo(p3)
                + w4 * blo(p4) + w5 * blo(p5) + w6 * blo(p6) + w7 * blo(p7);
            sy += w0 * bhi(p0) + w1 * bhi(p1) + w2 * bhi(p2) + w3 * bhi(p3)
                + w4 * bhi(p4) + w5 * bhi(p5) + w6 * bhi(p6) + w7 * bhi(p7);
        }
        for (; t < ne; ++t) {
            int st = __shfl(s, t); float wt = __shfl(w, t);
            unsigned p = xbu[st * 64 + lane];
            sx += wt * blo(p); sy += wt * bhi(p);
        }
    }
    float vx = di * sx, vy = di * sy;
    unsigned short hx = f2bf(vx), hy = f2bf(vy);
    unsigned short lx = f2bf(vx - bf2f(hx)), ly = f2bf(vy - bf2f(hy));
    yh[i * 64 + lane] = (unsigned)hx | ((unsigned)hy << 16);
    yl[i * 64 + lane] = (unsigned)lx | ((unsigned)ly << 16);
}

// ------- GEMM: out = relu(y @ W^T + b), split-bf16 MFMA, pre-converted inputs -------
// A (y rows) staged in LDS (reused by all 4 waves); B (W rows) loaded straight from
// global per wave (each wave owns a disjoint 16-row W slice -> no intra-block reuse).
// K=128 fully unrolled, single barrier.

#define LDK 136   // LDS K-stride (ushorts): 272B rows -> b128-aligned, bank-uniform frags

__global__ __launch_bounds__(256) void k_gemm(
        const unsigned short* __restrict__ yh, const unsigned short* __restrict__ yl,
        const unsigned short* __restrict__ Wh, const unsigned short* __restrict__ Wl,
        const float* __restrict__ bias, float* __restrict__ out) {
    __shared__ unsigned short Ah[64 * LDK], Al[64 * LDK];
    int tid = threadIdx.x;
    int lane = tid & 63;
    int wv = tid >> 6;
    int jb = blockIdx.x * 64;        // n fastest-varying -> y-tile reuse in L2
    int i0 = blockIdx.y * 64;
    int n0 = wv * 16;
    int rl = lane & 15;              // m (A) / n (B) within 16-tile
    int quad = lane >> 4;

    // B fragments from global (W slice is L2-resident)
    bf16x8 bh[4], bl[4];
    #pragma unroll
    for (int ks = 0; ks < 4; ++ks) {
        int off = (jb + n0 + rl) * IN_DIM + ks * 32 + quad * 8;
        bh[ks] = *(const bf16x8*)&Wh[off];
        bl[ks] = *(const bf16x8*)&Wl[off];
    }

    // stage A hi+lo (pure 16B copies)
    #pragma unroll
    for (int it = 0; it < 4; ++it) {
        int g = it * 256 + tid;      // 0..1023
        int r = g >> 4;              // 0..63
        int c8 = g & 15;             // ushort8 chunk along k
        int row = i0 + r; if (row >= N_NODES) row = N_NODES - 1;
        int ga = row * IN_DIM + c8 * 8;
        int la = r * LDK + c8 * 8;
        *(bf16x8*)&Ah[la] = *(const bf16x8*)&yh[ga];
        *(bf16x8*)&Al[la] = *(const bf16x8*)&yl[ga];
    }
    __syncthreads();

    f32x4 acc[4] = {{0.f,0.f,0.f,0.f},{0.f,0.f,0.f,0.f},{0.f,0.f,0.f,0.f},{0.f,0.f,0.f,0.f}};
    #pragma unroll
    for (int ks = 0; ks < 4; ++ks) {
        int koff = ks * 32 + quad * 8;
        #pragma unroll
        for (int mt = 0; mt < 4; ++mt) {
            bf16x8 ah = *(bf16x8*)&Ah[(mt * 16 + rl) * LDK + koff];
            bf16x8 al = *(bf16x8*)&Al[(mt * 16 + rl) * LDK + koff];
            acc[mt] = __builtin_amdgcn_mfma_f32_16x16x32_bf16(ah, bh[ks], acc[mt], 0, 0, 0);
            acc[mt] = __builtin_amdgcn_mfma_f32_16x16x32_bf16(ah, bl[ks], acc[mt], 0, 0, 0);
            acc[mt] = __builtin_amdgcn_mfma_f32_16x16x32_bf16(al, bh[ks], acc[mt], 0, 0, 0);
        }
    }

    float bv = bias[jb + n0 + rl];
    #pragma unroll
    for (int mt = 0; mt < 4; ++mt) {
        #pragma unroll
        for (int r = 0; r < 4; ++r) {
            int row = i0 + mt * 16 + quad * 4 + r;
            if (row < N_NODES) {
                float v = acc[mt][r] + bv;
                out[row * OUT_DIM + jb + n0 + rl] = fmaxf(v, 0.f);
            }
        }
    }
}

// ---------------- launch ----------------

extern "C" void kernel_launch(void* const* d_in, const int* in_sizes, int n_in,
                              void* d_out, int out_size, void* d_ws, size_t ws_size,
                              hipStream_t stream) {
    const float* x  = (const float*)d_in[0];
    const int*   ei = (const int*)d_in[1];
    const float* W  = (const float*)d_in[2];
    const float* b  = (const float*)d_in[3];
    float* out = (float*)d_out;

    char* ws = (char*)d_ws;
    int*            counts = (int*)(ws + 0);                   // 50000 ints
    int*            ptr    = (int*)(ws + 200704);              // 50000 ints
    int*            bsum   = (int*)(ws + 401408);              // 49 ints
    float*          dinv   = (float*)(ws + 401664);            // 50000 floats
    int*            srcl   = (int*)(ws + 602368);              // 800000 ints
    unsigned*       yh     = (unsigned*)(ws + 3802368);        // 12.8 MB
    unsigned*       yl     = (unsigned*)(ws + 16602368);       // 12.8 MB
    unsigned short* xb     = (unsigned short*)(ws + 29402368); // 12.8 MB
    unsigned short* Wh     = (unsigned short*)(ws + 42202368); // 64 KB
    unsigned short* Wl     = (unsigned short*)(ws + 42267904); // 64 KB

    hipMemsetAsync(counts, 0, N_NODES * sizeof(int), stream);

    k_prep<<<EDGE_BLOCKS + CONV_BLOCKS + WCONV_BLOCKS, 256, 0, stream>>>(
        ei, counts, x, xb, W, Wh, Wl);
    k_scan1<<<SCAN_BLOCKS, 1024, 0, stream>>>(counts, ptr, bsum);
    k_finalize<<<(N_NODES + 255) / 256, 256, 0, stream>>>(ptr, counts, bsum, dinv);
    k_scatter<<<EDGE_BLOCKS, 256, 0, stream>>>(ei, ptr, srcl);
    k_aggregate<<<(N_NODES + 3) / 4, 256, 0, stream>>>((const unsigned*)xb, dinv, ptr,
                                                       counts, srcl, yh, yl);
    dim3 g(OUT_DIM / 64, (N_NODES + 63) / 64);
    k_gemm<<<g, 256, 0, stream>>>((const unsigned short*)yh, (const unsigned short*)yl,
                                  Wh, Wl, b, out);
}

// Round 5
// 233.859 us; speedup vs baseline: 1.5113x; 1.0128x over previous
//
#include <hip/hip_runtime.h>

#define N_NODES 50000
#define IN_DIM  128
#define OUT_DIM 256
#define N_EDGES 800000
#define HIST_BLOCKS 391    // ceil(800000/(256*8)) edges, 8/thread
#define CONV_BLOCKS 3125   // (N_NODES*IN_DIM/8)/256
#define WCONV_BLOCKS 16    // (OUT_DIM*IN_DIM/8)/256
#define SCAN_BLOCKS 49     // ceil(50000/1024)
#define SCAT_BLOCKS 782    // ceil(800000/(256*4)) edges, 4/thread

typedef short bf16x8 __attribute__((ext_vector_type(8)));   // 8 bf16 = 4 VGPRs
typedef float f32x4  __attribute__((ext_vector_type(4)));   // MFMA acc
typedef unsigned short ushort8_t __attribute__((ext_vector_type(8)));

__device__ __forceinline__ unsigned short f2bf(float f) {
    unsigned u = __float_as_uint(f);
    return (unsigned short)((u + 0x7fffu + ((u >> 16) & 1u)) >> 16);
}
__device__ __forceinline__ float bf2f(unsigned short h) {
    return __uint_as_float(((unsigned)h) << 16);
}

// ---- prep: dst histogram (8 edges/thread) + x->bf16 + W->split-bf16 (fused grid) ----

__global__ __launch_bounds__(256) void k_prep(const int* __restrict__ ei,
                                              int* __restrict__ counts,
                                              const float* __restrict__ x,
                                              unsigned short* __restrict__ xb,
                                              const float* __restrict__ W,
                                              unsigned short* __restrict__ Wh,
                                              unsigned short* __restrict__ Wl) {
    int b = blockIdx.x;
    if (b < HIST_BLOCKS) {
        int t = b * 256 + threadIdx.x;
        if (t * 8 < N_EDGES) {                 // N_EDGES % 8 == 0, full groups
            int e2 = t * 16;                   // element index into ei
            int4 a = *(const int4*)&ei[e2];
            int4 c = *(const int4*)&ei[e2 + 4];
            int4 d = *(const int4*)&ei[e2 + 8];
            int4 f = *(const int4*)&ei[e2 + 12];
            atomicAdd(&counts[a.y], 1); atomicAdd(&counts[a.w], 1);
            atomicAdd(&counts[c.y], 1); atomicAdd(&counts[c.w], 1);
            atomicAdd(&counts[d.y], 1); atomicAdd(&counts[d.w], 1);
            atomicAdd(&counts[f.y], 1); atomicAdd(&counts[f.w], 1);
        }
    } else if (b < HIST_BLOCKS + CONV_BLOCKS) {
        int t = (b - HIST_BLOCKS) * 256 + threadIdx.x;
        int base = t * 8;
        float4 a = *(const float4*)&x[base];
        float4 c = *(const float4*)&x[base + 4];
        ushort8_t o;
        o[0] = f2bf(a.x); o[1] = f2bf(a.y); o[2] = f2bf(a.z); o[3] = f2bf(a.w);
        o[4] = f2bf(c.x); o[5] = f2bf(c.y); o[6] = f2bf(c.z); o[7] = f2bf(c.w);
        *(ushort8_t*)&xb[base] = o;
    } else {
        int t = (b - HIST_BLOCKS - CONV_BLOCKS) * 256 + threadIdx.x;
        int base = t * 8;
        float4 a = *(const float4*)&W[base];
        float4 c = *(const float4*)&W[base + 4];
        ushort8_t h, l;
        h[0] = f2bf(a.x); h[1] = f2bf(a.y); h[2] = f2bf(a.z); h[3] = f2bf(a.w);
        h[4] = f2bf(c.x); h[5] = f2bf(c.y); h[6] = f2bf(c.z); h[7] = f2bf(c.w);
        l[0] = f2bf(a.x - bf2f(h[0])); l[1] = f2bf(a.y - bf2f(h[1]));
        l[2] = f2bf(a.z - bf2f(h[2])); l[3] = f2bf(a.w - bf2f(h[3]));
        l[4] = f2bf(c.x - bf2f(h[4])); l[5] = f2bf(c.y - bf2f(h[5]));
        l[6] = f2bf(c.z - bf2f(h[6])); l[7] = f2bf(c.w - bf2f(h[7]));
        *(ushort8_t*)&Wh[base] = h;
        *(ushort8_t*)&Wl[base] = l;
    }
}

// ---- single-pass scan w/ decoupled lookback: counts -> exclusive ptr + dinv ----
// flags[b] = block b total | 0x40000000 (ready bit; totals < 2^30). Block b polls
// only blocks < b (49 blocks, all co-resident). Device-scope atomics = coherent.

__global__ __launch_bounds__(1024) void k_scan(const int* __restrict__ counts,
                                               int* __restrict__ ptr,
                                               float* __restrict__ dinv,
                                               int* __restrict__ flags) {
    __shared__ int lds[1024];
    __shared__ int s_prefix;
    int b = blockIdx.x, t = threadIdx.x;
    int i = b * 1024 + t;
    int c = (i < N_NODES) ? counts[i] : 0;
    lds[t] = c;
    __syncthreads();
    for (int off = 1; off < 1024; off <<= 1) {
        int v = (t >= off) ? lds[t - off] : 0;
        __syncthreads();
        lds[t] += v;
        __syncthreads();
    }
    if (t == 1023) atomicExch(&flags[b], lds[1023] | 0x40000000);
    if (t < 64) {                              // wave 0: sum earlier blocks' totals
        int v = 0;
        if (t < b) {
            do { v = atomicAdd(&flags[t], 0); } while (v == 0);
            v &= 0x3fffffff;
        }
        for (int off = 32; off; off >>= 1) v += __shfl_down(v, off);
        if (t == 0) s_prefix = v;
    }
    __syncthreads();
    if (i < N_NODES) {
        ptr[i] = s_prefix + lds[t] - c;        // exclusive start (cursor)
        dinv[i] = rsqrtf((float)(c + 1));      // +1 self-loop
    }
}

// ---- scatter, 4 edges/thread: 4 independent atomic+store chains in flight ----

__global__ __launch_bounds__(256) void k_scatter(const int* __restrict__ ei,
                                                 int* __restrict__ ptr,
                                                 int* __restrict__ srcl) {
    int t = blockIdx.x * 256 + threadIdx.x;
    if (t * 4 >= N_EDGES) return;              // N_EDGES % 4 == 0, full groups
    int e2 = t * 8;
    int4 a = *(const int4*)&ei[e2];            // (s0,d0,s1,d1)
    int4 c = *(const int4*)&ei[e2 + 4];        // (s2,d2,s3,d3)
    int p0 = atomicAdd(&ptr[a.y], 1);
    int p1 = atomicAdd(&ptr[a.w], 1);
    int p2 = atomicAdd(&ptr[c.y], 1);
    int p3 = atomicAdd(&ptr[c.w], 1);
    srcl[p0] = a.x;
    srcl[p1] = a.z;
    srcl[p2] = c.x;
    srcl[p3] = c.z;
}

// -------- aggregation: y[i] = dinv[i]*(dinv[i]*x[i] + sum_s dinv[s]*x[s]) --------
// wave-per-node, bf16 gather, shfl-broadcast, 8x batch; writes split-bf16 yh/yl.

__device__ __forceinline__ float blo(unsigned p) { return __uint_as_float(p << 16); }
__device__ __forceinline__ float bhi(unsigned p) { return __uint_as_float(p & 0xffff0000u); }

__global__ __launch_bounds__(256) void k_aggregate(
        const unsigned* __restrict__ xbu, const float* __restrict__ dinv,
        const int* __restrict__ ptr, const int* __restrict__ counts,
        const int* __restrict__ srcl,
        unsigned* __restrict__ yh, unsigned* __restrict__ yl) {
    int wv = threadIdx.x >> 6;
    int lane = threadIdx.x & 63;
    int i = blockIdx.x * 4 + wv;
    if (i >= N_NODES) return;
    float di = dinv[i];
    int end = ptr[i];
    int start = end - counts[i];
    unsigned pself = xbu[i * 64 + lane];
    float sx = di * blo(pself), sy = di * bhi(pself);     // self-loop term
    for (int e0 = start; e0 < end; e0 += 64) {
        int ne = end - e0; if (ne > 64) ne = 64;
        int s = 0; float w = 0.f;
        if (lane < ne) {
            s = srcl[e0 + lane];
            w = dinv[s];
        }
        int t = 0;
        for (; t + 8 <= ne; t += 8) {
            int s0 = __shfl(s, t),     s1 = __shfl(s, t + 1);
            int s2 = __shfl(s, t + 2), s3 = __shfl(s, t + 3);
            int s4 = __shfl(s, t + 4), s5 = __shfl(s, t + 5);
            int s6 = __shfl(s, t + 6), s7 = __shfl(s, t + 7);
            float w0 = __shfl(w, t),     w1 = __shfl(w, t + 1);
            float w2 = __shfl(w, t + 2), w3 = __shfl(w, t + 3);
            float w4 = __shfl(w, t + 4), w5 = __shfl(w, t + 5);
            float w6 = __shfl(w, t + 6), w7 = __shfl(w, t + 7);
            unsigned p0 = xbu[s0 * 64 + lane], p1 = xbu[s1 * 64 + lane];
            unsigned p2 = xbu[s2 * 64 + lane], p3 = xbu[s3 * 64 + lane];
            unsigned p4 = xbu[s4 * 64 + lane], p5 = xbu[s5 * 64 + lane];
            unsigned p6 = xbu[s6 * 64 + lane], p7 = xbu[s7 * 64 + lane];
            sx += w0 * blo(p0) + w1 * blo(p1) + w2 * blo(p2) + w3 * blo(p3)
                + w4 * blo(p4) + w5 * blo(p5) + w6 * blo(p6) + w7 * blo(p7);
            sy += w0 * bhi(p0) + w1 * bhi(p1) + w2 * bhi(p2) + w3 * bhi(p3)
                + w4 * bhi(p4) + w5 * bhi(p5) + w6 * bhi(p6) + w7 * bhi(p7);
        }
        for (; t < ne; ++t) {
            int st = __shfl(s, t); float wt = __shfl(w, t);
            unsigned p = xbu[st * 64 + lane];
            sx += wt * blo(p); sy += wt * bhi(p);
        }
    }
    float vx = di * sx, vy = di * sy;
    unsigned short hx = f2bf(vx), hy = f2bf(vy);
    unsigned short lx = f2bf(vx - bf2f(hx)), ly = f2bf(vy - bf2f(hy));
    yh[i * 64 + lane] = (unsigned)hx | ((unsigned)hy << 16);
    yl[i * 64 + lane] = (unsigned)lx | ((unsigned)ly << 16);
}

// ------- GEMM: out = relu(y @ W^T + b), split-bf16 MFMA, pre-converted inputs -------

#define LDK 136   // LDS K-stride (ushorts): 272B rows -> b128-aligned, bank-uniform frags

__global__ __launch_bounds__(256) void k_gemm(
        const unsigned short* __restrict__ yh, const unsigned short* __restrict__ yl,
        const unsigned short* __restrict__ Wh, const unsigned short* __restrict__ Wl,
        const float* __restrict__ bias, float* __restrict__ out) {
    __shared__ unsigned short Ah[64 * LDK], Al[64 * LDK];
    int tid = threadIdx.x;
    int lane = tid & 63;
    int wv = tid >> 6;
    int jb = blockIdx.x * 64;        // n fastest-varying -> y-tile reuse in L2
    int i0 = blockIdx.y * 64;
    int n0 = wv * 16;
    int rl = lane & 15;              // m (A) / n (B) within 16-tile
    int quad = lane >> 4;

    bf16x8 bh[4], bl[4];
    #pragma unroll
    for (int ks = 0; ks < 4; ++ks) {
        int off = (jb + n0 + rl) * IN_DIM + ks * 32 + quad * 8;
        bh[ks] = *(const bf16x8*)&Wh[off];
        bl[ks] = *(const bf16x8*)&Wl[off];
    }

    #pragma unroll
    for (int it = 0; it < 4; ++it) {
        int g = it * 256 + tid;      // 0..1023
        int r = g >> 4;              // 0..63
        int c8 = g & 15;             // ushort8 chunk along k
        int row = i0 + r; if (row >= N_NODES) row = N_NODES - 1;
        int ga = row * IN_DIM + c8 * 8;
        int la = r * LDK + c8 * 8;
        *(bf16x8*)&Ah[la] = *(const bf16x8*)&yh[ga];
        *(bf16x8*)&Al[la] = *(const bf16x8*)&yl[ga];
    }
    __syncthreads();

    f32x4 acc[4] = {{0.f,0.f,0.f,0.f},{0.f,0.f,0.f,0.f},{0.f,0.f,0.f,0.f},{0.f,0.f,0.f,0.f}};
    #pragma unroll
    for (int ks = 0; ks < 4; ++ks) {
        int koff = ks * 32 + quad * 8;
        #pragma unroll
        for (int mt = 0; mt < 4; ++mt) {
            bf16x8 ah = *(bf16x8*)&Ah[(mt * 16 + rl) * LDK + koff];
            bf16x8 al = *(bf16x8*)&Al[(mt * 16 + rl) * LDK + koff];
            acc[mt] = __builtin_amdgcn_mfma_f32_16x16x32_bf16(ah, bh[ks], acc[mt], 0, 0, 0);
            acc[mt] = __builtin_amdgcn_mfma_f32_16x16x32_bf16(ah, bl[ks], acc[mt], 0, 0, 0);
            acc[mt] = __builtin_amdgcn_mfma_f32_16x16x32_bf16(al, bh[ks], acc[mt], 0, 0, 0);
        }
    }

    float bv = bias[jb + n0 + rl];
    #pragma unroll
    for (int mt = 0; mt < 4; ++mt) {
        #pragma unroll
        for (int r = 0; r < 4; ++r) {
            int row = i0 + mt * 16 + quad * 4 + r;
            if (row < N_NODES) {
                float v = acc[mt][r] + bv;
                out[row * OUT_DIM + jb + n0 + rl] = fmaxf(v, 0.f);
            }
        }
    }
}

// ---------------- launch ----------------

extern "C" void kernel_launch(void* const* d_in, const int* in_sizes, int n_in,
                              void* d_out, int out_size, void* d_ws, size_t ws_size,
                              hipStream_t stream) {
    const float* x  = (const float*)d_in[0];
    const int*   ei = (const int*)d_in[1];
    const float* W  = (const float*)d_in[2];
    const float* b  = (const float*)d_in[3];
    float* out = (float*)d_out;

    char* ws = (char*)d_ws;
    int*            counts = (int*)(ws + 0);                   // 50000 ints
    int*            flags  = (int*)(ws + 200704);              // 49 ints (scan lookback)
    int*            ptr    = (int*)(ws + 201728);              // 50000 ints
    float*          dinv   = (float*)(ws + 402432);            // 50000 floats
    int*            srcl   = (int*)(ws + 603136);              // 800000 ints
    unsigned*       yh     = (unsigned*)(ws + 3803136);        // 12.8 MB
    unsigned*       yl     = (unsigned*)(ws + 16603136);       // 12.8 MB
    unsigned short* xb     = (unsigned short*)(ws + 29403136); // 12.8 MB
    unsigned short* Wh     = (unsigned short*)(ws + 42203136); // 64 KB
    unsigned short* Wl     = (unsigned short*)(ws + 42268672); // 64 KB

    hipMemsetAsync(counts, 0, 201728, stream);                 // counts + flags

    k_prep<<<HIST_BLOCKS + CONV_BLOCKS + WCONV_BLOCKS, 256, 0, stream>>>(
        ei, counts, x, xb, W, Wh, Wl);
    k_scan<<<SCAN_BLOCKS, 1024, 0, stream>>>(counts, ptr, dinv, flags);
    k_scatter<<<SCAT_BLOCKS, 256, 0, stream>>>(ei, ptr, srcl);
    k_aggregate<<<(N_NODES + 3) / 4, 256, 0, stream>>>((const unsigned*)xb, dinv, ptr,
                                                       counts, srcl, yh, yl);
    dim3 g(OUT_DIM / 64, (N_NODES + 63) / 64);
    k_gemm<<<g, 256, 0, stream>>>((const unsigned short*)yh, (const unsigned short*)yl,
                                  Wh, Wl, b, out);
}

// Round 6
// 214.731 us; speedup vs baseline: 1.6459x; 1.0891x over previous
//
#include <hip/hip_runtime.h>

#define N_NODES 50000
#define IN_DIM  128
#define OUT_DIM 256
#define N_EDGES 800000
#define HIST_BLOCKS 391    // ceil(800000/(256*8)) edges, 8/thread
#define CONV_BLOCKS 3125   // (N_NODES*IN_DIM/8)/256
#define WCONV_BLOCKS 16    // (OUT_DIM*IN_DIM/8)/256
#define SCAN_BLOCKS 49     // ceil(50000/1024)
#define N_BUCKETS 391      // 128-node ranges
#define BINA_BLOCKS 128    // 6250 edges each (exact)
#define EDGES_PER_BINA 6250

typedef short bf16x8 __attribute__((ext_vector_type(8)));   // 8 bf16 = 4 VGPRs
typedef float f32x4  __attribute__((ext_vector_type(4)));   // MFMA acc
typedef unsigned short ushort8_t __attribute__((ext_vector_type(8)));

__device__ __forceinline__ unsigned short f2bf(float f) {
    unsigned u = __float_as_uint(f);
    return (unsigned short)((u + 0x7fffu + ((u >> 16) & 1u)) >> 16);
}
__device__ __forceinline__ float bf2f(unsigned short h) {
    return __uint_as_float(((unsigned)h) << 16);
}

// ---- prep: dst histogram (8 edges/thread) + x->bf16 + W->split-bf16 (fused grid) ----

__global__ __launch_bounds__(256) void k_prep(const int* __restrict__ ei,
                                              int* __restrict__ counts,
                                              const float* __restrict__ x,
                                              unsigned short* __restrict__ xb,
                                              const float* __restrict__ W,
                                              unsigned short* __restrict__ Wh,
                                              unsigned short* __restrict__ Wl) {
    int b = blockIdx.x;
    if (b < HIST_BLOCKS) {
        int t = b * 256 + threadIdx.x;
        if (t * 8 < N_EDGES) {                 // N_EDGES % 8 == 0, full groups
            int e2 = t * 16;
            int4 a = *(const int4*)&ei[e2];
            int4 c = *(const int4*)&ei[e2 + 4];
            int4 d = *(const int4*)&ei[e2 + 8];
            int4 f = *(const int4*)&ei[e2 + 12];
            atomicAdd(&counts[a.y], 1); atomicAdd(&counts[a.w], 1);
            atomicAdd(&counts[c.y], 1); atomicAdd(&counts[c.w], 1);
            atomicAdd(&counts[d.y], 1); atomicAdd(&counts[d.w], 1);
            atomicAdd(&counts[f.y], 1); atomicAdd(&counts[f.w], 1);
        }
    } else if (b < HIST_BLOCKS + CONV_BLOCKS) {
        int t = (b - HIST_BLOCKS) * 256 + threadIdx.x;
        int base = t * 8;
        float4 a = *(const float4*)&x[base];
        float4 c = *(const float4*)&x[base + 4];
        ushort8_t o;
        o[0] = f2bf(a.x); o[1] = f2bf(a.y); o[2] = f2bf(a.z); o[3] = f2bf(a.w);
        o[4] = f2bf(c.x); o[5] = f2bf(c.y); o[6] = f2bf(c.z); o[7] = f2bf(c.w);
        *(ushort8_t*)&xb[base] = o;
    } else {
        int t = (b - HIST_BLOCKS - CONV_BLOCKS) * 256 + threadIdx.x;
        int base = t * 8;
        float4 a = *(const float4*)&W[base];
        float4 c = *(const float4*)&W[base + 4];
        ushort8_t h, l;
        h[0] = f2bf(a.x); h[1] = f2bf(a.y); h[2] = f2bf(a.z); h[3] = f2bf(a.w);
        h[4] = f2bf(c.x); h[5] = f2bf(c.y); h[6] = f2bf(c.z); h[7] = f2bf(c.w);
        l[0] = f2bf(a.x - bf2f(h[0])); l[1] = f2bf(a.y - bf2f(h[1]));
        l[2] = f2bf(a.z - bf2f(h[2])); l[3] = f2bf(a.w - bf2f(h[3]));
        l[4] = f2bf(c.x - bf2f(h[4])); l[5] = f2bf(c.y - bf2f(h[5]));
        l[6] = f2bf(c.z - bf2f(h[6])); l[7] = f2bf(c.w - bf2f(h[7]));
        *(ushort8_t*)&Wh[base] = h;
        *(ushort8_t*)&Wl[base] = l;
    }
}

// ---- single-pass scan w/ decoupled lookback: counts -> exclusive ptr + dinv ----
// Also emits bcur[b] = CSR start of bucket b (node range [128b, 128b+128)).

__global__ __launch_bounds__(1024) void k_scan(const int* __restrict__ counts,
                                               int* __restrict__ ptr,
                                               float* __restrict__ dinv,
                                               int* __restrict__ flags,
                                               int* __restrict__ bcur) {
    __shared__ int lds[1024];
    __shared__ int s_prefix;
    int b = blockIdx.x, t = threadIdx.x;
    int i = b * 1024 + t;
    int c = (i < N_NODES) ? counts[i] : 0;
    lds[t] = c;
    __syncthreads();
    for (int off = 1; off < 1024; off <<= 1) {
        int v = (t >= off) ? lds[t - off] : 0;
        __syncthreads();
        lds[t] += v;
        __syncthreads();
    }
    if (t == 1023) atomicExch(&flags[b], lds[1023] | 0x40000000);
    if (t < 64) {                              // wave 0: sum earlier blocks' totals
        int v = 0;
        if (t < b) {
            do { v = atomicAdd(&flags[t], 0); } while (v == 0);
            v &= 0x3fffffff;
        }
        for (int off = 32; off; off >>= 1) v += __shfl_down(v, off);
        if (t == 0) s_prefix = v;
    }
    __syncthreads();
    if (i < N_NODES) {
        int ex = s_prefix + lds[t] - c;        // exclusive start
        ptr[i] = ex;
        if ((i & 127) == 0) bcur[i >> 7] = ex; // bucket base cursor
        dinv[i] = rsqrtf((float)(c + 1));      // +1 self-loop
    }
}

// ---- binned scatter pass A: edges -> bucket-grouped packed array ----
// pack = (dst&127)<<16 | src   (src < 2^16, local < 2^7)

__global__ __launch_bounds__(256) void k_binA(const int* __restrict__ ei,
                                              int* __restrict__ bcur,
                                              unsigned* __restrict__ bucketed) {
    __shared__ int hist[N_BUCKETS];
    __shared__ int cursor[N_BUCKETS];
    int tid = threadIdx.x;
    int base = blockIdx.x * EDGES_PER_BINA;
    for (int t = tid; t < N_BUCKETS; t += 256) hist[t] = 0;
    __syncthreads();
    for (int e = tid; e < EDGES_PER_BINA; e += 256) {
        int2 p = *(const int2*)&ei[2 * (base + e)];
        atomicAdd(&hist[p.y >> 7], 1);
    }
    __syncthreads();
    for (int t = tid; t < N_BUCKETS; t += 256) {
        int cnt = hist[t];
        cursor[t] = (cnt > 0) ? atomicAdd(&bcur[t], cnt) : 0;
    }
    __syncthreads();
    for (int e = tid; e < EDGES_PER_BINA; e += 256) {
        int2 p = *(const int2*)&ei[2 * (base + e)];
        int pos = atomicAdd(&cursor[p.y >> 7], 1);
        bucketed[pos] = ((unsigned)(p.y & 127) << 16) | (unsigned)p.x;
    }
}

// ---- binned scatter pass B: bucket -> per-node CSR srcl (single-owner region) ----

__global__ __launch_bounds__(256) void k_binB(const unsigned* __restrict__ bucketed,
                                              const int* __restrict__ ptr,
                                              int* __restrict__ srcl) {
    __shared__ int cur[128];
    int b = blockIdx.x, tid = threadIdx.x;
    int node0 = b << 7;
    if (tid < 128) {
        int n = node0 + tid;
        cur[tid] = (n < N_NODES) ? ptr[n] : 0;
    }
    __syncthreads();
    int start = ptr[node0];
    int nend = node0 + 128;
    int end = (nend < N_NODES) ? ptr[nend] : N_EDGES;
    for (int e = start + tid; e < end; e += 256) {
        unsigned p = bucketed[e];
        int pos = atomicAdd(&cur[p >> 16], 1);
        srcl[pos] = (int)(p & 0xffffu);
    }
}

// -------- aggregation: y[i] = dinv[i]*(dinv[i]*x[i] + sum_s dinv[s]*x[s]) --------
// wave-per-node, bf16 gather, shfl-broadcast, 8x batch; writes split-bf16 yh/yl.
// NOTE: ptr is now the unmutated exclusive START (binB uses LDS cursors).

__device__ __forceinline__ float blo(unsigned p) { return __uint_as_float(p << 16); }
__device__ __forceinline__ float bhi(unsigned p) { return __uint_as_float(p & 0xffff0000u); }

__global__ __launch_bounds__(256) void k_aggregate(
        const unsigned* __restrict__ xbu, const float* __restrict__ dinv,
        const int* __restrict__ ptr, const int* __restrict__ counts,
        const int* __restrict__ srcl,
        unsigned* __restrict__ yh, unsigned* __restrict__ yl) {
    int wv = threadIdx.x >> 6;
    int lane = threadIdx.x & 63;
    int i = blockIdx.x * 4 + wv;
    if (i >= N_NODES) return;
    float di = dinv[i];
    int start = ptr[i];
    int end = start + counts[i];
    unsigned pself = xbu[i * 64 + lane];
    float sx = di * blo(pself), sy = di * bhi(pself);     // self-loop term
    for (int e0 = start; e0 < end; e0 += 64) {
        int ne = end - e0; if (ne > 64) ne = 64;
        int s = 0; float w = 0.f;
        if (lane < ne) {
            s = srcl[e0 + lane];
            w = dinv[s];
        }
        int t = 0;
        for (; t + 8 <= ne; t += 8) {
            int s0 = __shfl(s, t),     s1 = __shfl(s, t + 1);
            int s2 = __shfl(s, t + 2), s3 = __shfl(s, t + 3);
            int s4 = __shfl(s, t + 4), s5 = __shfl(s, t + 5);
            int s6 = __shfl(s, t + 6), s7 = __shfl(s, t + 7);
            float w0 = __shfl(w, t),     w1 = __shfl(w, t + 1);
            float w2 = __shfl(w, t + 2), w3 = __shfl(w, t + 3);
            float w4 = __shfl(w, t + 4), w5 = __shfl(w, t + 5);
            float w6 = __shfl(w, t + 6), w7 = __shfl(w, t + 7);
            unsigned p0 = xbu[s0 * 64 + lane], p1 = xbu[s1 * 64 + lane];
            unsigned p2 = xbu[s2 * 64 + lane], p3 = xbu[s3 * 64 + lane];
            unsigned p4 = xbu[s4 * 64 + lane], p5 = xbu[s5 * 64 + lane];
            unsigned p6 = xbu[s6 * 64 + lane], p7 = xbu[s7 * 64 + lane];
            sx += w0 * blo(p0) + w1 * blo(p1) + w2 * blo(p2) + w3 * blo(p3)
                + w4 * blo(p4) + w5 * blo(p5) + w6 * blo(p6) + w7 * blo(p7);
            sy += w0 * bhi(p0) + w1 * bhi(p1) + w2 * bhi(p2) + w3 * bhi(p3)
                + w4 * bhi(p4) + w5 * bhi(p5) + w6 * bhi(p6) + w7 * bhi(p7);
        }
        for (; t < ne; ++t) {
            int st = __shfl(s, t); float wt = __shfl(w, t);
            unsigned p = xbu[st * 64 + lane];
            sx += wt * blo(p); sy += wt * bhi(p);
        }
    }
    float vx = di * sx, vy = di * sy;
    unsigned short hx = f2bf(vx), hy = f2bf(vy);
    unsigned short lx = f2bf(vx - bf2f(hx)), ly = f2bf(vy - bf2f(hy));
    yh[i * 64 + lane] = (unsigned)hx | ((unsigned)hy << 16);
    yl[i * 64 + lane] = (unsigned)lx | ((unsigned)ly << 16);
}

// ------- GEMM: out = relu(y @ W^T + b), split-bf16 MFMA, pre-converted inputs -------

#define LDK 136   // LDS K-stride (ushorts): 272B rows -> b128-aligned, bank-uniform frags

__global__ __launch_bounds__(256) void k_gemm(
        const unsigned short* __restrict__ yh, const unsigned short* __restrict__ yl,
        const unsigned short* __restrict__ Wh, const unsigned short* __restrict__ Wl,
        const float* __restrict__ bias, float* __restrict__ out) {
    __shared__ unsigned short Ah[64 * LDK], Al[64 * LDK];
    int tid = threadIdx.x;
    int lane = tid & 63;
    int wv = tid >> 6;
    int jb = blockIdx.x * 64;        // n fastest-varying -> y-tile reuse in L2
    int i0 = blockIdx.y * 64;
    int n0 = wv * 16;
    int rl = lane & 15;              // m (A) / n (B) within 16-tile
    int quad = lane >> 4;

    bf16x8 bh[4], bl[4];
    #pragma unroll
    for (int ks = 0; ks < 4; ++ks) {
        int off = (jb + n0 + rl) * IN_DIM + ks * 32 + quad * 8;
        bh[ks] = *(const bf16x8*)&Wh[off];
        bl[ks] = *(const bf16x8*)&Wl[off];
    }

    #pragma unroll
    for (int it = 0; it < 4; ++it) {
        int g = it * 256 + tid;      // 0..1023
        int r = g >> 4;              // 0..63
        int c8 = g & 15;             // ushort8 chunk along k
        int row = i0 + r; if (row >= N_NODES) row = N_NODES - 1;
        int ga = row * IN_DIM + c8 * 8;
        int la = r * LDK + c8 * 8;
        *(bf16x8*)&Ah[la] = *(const bf16x8*)&yh[ga];
        *(bf16x8*)&Al[la] = *(const bf16x8*)&yl[ga];
    }
    __syncthreads();

    f32x4 acc[4] = {{0.f,0.f,0.f,0.f},{0.f,0.f,0.f,0.f},{0.f,0.f,0.f,0.f},{0.f,0.f,0.f,0.f}};
    #pragma unroll
    for (int ks = 0; ks < 4; ++ks) {
        int koff = ks * 32 + quad * 8;
        #pragma unroll
        for (int mt = 0; mt < 4; ++mt) {
            bf16x8 ah = *(bf16x8*)&Ah[(mt * 16 + rl) * LDK + koff];
            bf16x8 al = *(bf16x8*)&Al[(mt * 16 + rl) * LDK + koff];
            acc[mt] = __builtin_amdgcn_mfma_f32_16x16x32_bf16(ah, bh[ks], acc[mt], 0, 0, 0);
            acc[mt] = __builtin_amdgcn_mfma_f32_16x16x32_bf16(ah, bl[ks], acc[mt], 0, 0, 0);
            acc[mt] = __builtin_amdgcn_mfma_f32_16x16x32_bf16(al, bh[ks], acc[mt], 0, 0, 0);
        }
    }

    float bv = bias[jb + n0 + rl];
    #pragma unroll
    for (int mt = 0; mt < 4; ++mt) {
        #pragma unroll
        for (int r = 0; r < 4; ++r) {
            int row = i0 + mt * 16 + quad * 4 + r;
            if (row < N_NODES) {
                float v = acc[mt][r] + bv;
                out[row * OUT_DIM + jb + n0 + rl] = fmaxf(v, 0.f);
            }
        }
    }
}

// ---------------- launch ----------------

extern "C" void kernel_launch(void* const* d_in, const int* in_sizes, int n_in,
                              void* d_out, int out_size, void* d_ws, size_t ws_size,
                              hipStream_t stream) {
    const float* x  = (const float*)d_in[0];
    const int*   ei = (const int*)d_in[1];
    const float* W  = (const float*)d_in[2];
    const float* b  = (const float*)d_in[3];
    float* out = (float*)d_out;

    char* ws = (char*)d_ws;
    int*            counts   = (int*)(ws + 0);                   // 50000 ints
    int*            flags    = (int*)(ws + 200704);              // 49 ints (scan lookback)
    int*            bcur     = (int*)(ws + 201728);              // 391 ints (bucket cursors)
    int*            ptr      = (int*)(ws + 203776);              // 50000 ints
    float*          dinv     = (float*)(ws + 404480);            // 50000 floats
    int*            srcl     = (int*)(ws + 605184);              // 800000 ints
    unsigned*       bucketed = (unsigned*)(ws + 3805184);        // 800000 u32
    unsigned*       yh       = (unsigned*)(ws + 7005184);        // 12.8 MB
    unsigned*       yl       = (unsigned*)(ws + 19805184);       // 12.8 MB
    unsigned short* xb       = (unsigned short*)(ws + 32605184); // 12.8 MB
    unsigned short* Wh       = (unsigned short*)(ws + 45405184); // 64 KB
    unsigned short* Wl       = (unsigned short*)(ws + 45470720); // 64 KB

    hipMemsetAsync(counts, 0, 201728, stream);                   // counts + flags

    k_prep<<<HIST_BLOCKS + CONV_BLOCKS + WCONV_BLOCKS, 256, 0, stream>>>(
        ei, counts, x, xb, W, Wh, Wl);
    k_scan<<<SCAN_BLOCKS, 1024, 0, stream>>>(counts, ptr, dinv, flags, bcur);
    k_binA<<<BINA_BLOCKS, 256, 0, stream>>>(ei, bcur, bucketed);
    k_binB<<<N_BUCKETS, 256, 0, stream>>>(bucketed, ptr, srcl);
    k_aggregate<<<(N_NODES + 3) / 4, 256, 0, stream>>>((const unsigned*)xb, dinv, ptr,
                                                       counts, srcl, yh, yl);
    dim3 g(OUT_DIM / 64, (N_NODES + 63) / 64);
    k_gemm<<<g, 256, 0, stream>>>((const unsigned short*)yh, (const unsigned short*)yl,
                                  Wh, Wl, b, out);
}

// Round 7
// 203.325 us; speedup vs baseline: 1.7382x; 1.0561x over previous
//
#include <hip/hip_runtime.h>

#define N_NODES 50000
#define IN_DIM  128
#define OUT_DIM 256
#define N_EDGES 800000
#define CONV_BLOCKS 3125   // (N_NODES*IN_DIM/8)/256
#define WCONV_BLOCKS 16    // (OUT_DIM*IN_DIM/8)/256
#define BINA_BLOCKS 128    // 6250 edges each (exact)
#define EDGES_PER_BINA 6250
#define N_BUCKETS 782      // 64-node ranges (ceil(50000/64))
#define BUCKET_CAP 1280    // mean 1023, sd ~32 -> +8 sigma margin

typedef short bf16x8 __attribute__((ext_vector_type(8)));   // 8 bf16 = 4 VGPRs
typedef float f32x4  __attribute__((ext_vector_type(4)));   // MFMA acc
typedef unsigned short ushort8_t __attribute__((ext_vector_type(8)));

__device__ __forceinline__ unsigned short f2bf(float f) {
    unsigned u = __float_as_uint(f);
    return (unsigned short)((u + 0x7fffu + ((u >> 16) & 1u)) >> 16);
}
__device__ __forceinline__ float bf2f(unsigned short h) {
    return __uint_as_float(((unsigned)h) << 16);
}
__device__ __forceinline__ float blo(unsigned p) { return __uint_as_float(p << 16); }
__device__ __forceinline__ float bhi(unsigned p) { return __uint_as_float(p & 0xffff0000u); }

// ---- fused prep: [binA: hist + bucket-bin] | [x->bf16] | [W->split-bf16] ----
// binA blocks first (longest pole; they gate aggregate).
// pack = (dst&63)<<16 | src   (src < 2^16 since N_NODES=50000, local < 2^6)

__global__ __launch_bounds__(256) void k_prep(const int* __restrict__ ei,
                                              int* __restrict__ counts,
                                              int* __restrict__ bcnt,
                                              unsigned* __restrict__ bucketed,
                                              const float* __restrict__ x,
                                              unsigned short* __restrict__ xb,
                                              const float* __restrict__ W,
                                              unsigned short* __restrict__ Wh,
                                              unsigned short* __restrict__ Wl) {
    __shared__ int hist[N_BUCKETS];
    __shared__ int cursor[N_BUCKETS];
    int b = blockIdx.x, tid = threadIdx.x;
    if (b < BINA_BLOCKS) {
        int base = b * EDGES_PER_BINA;
        for (int t = tid; t < N_BUCKETS; t += 256) hist[t] = 0;
        __syncthreads();
        for (int e = tid; e < EDGES_PER_BINA; e += 256) {
            int2 p = *(const int2*)&ei[2 * (base + e)];
            atomicAdd(&counts[p.y], 1);        // global deg histogram (no return use)
            atomicAdd(&hist[p.y >> 6], 1);     // LDS bucket histogram
        }
        __syncthreads();
        for (int t = tid; t < N_BUCKETS; t += 256) {
            int cnt = hist[t];
            cursor[t] = t * BUCKET_CAP + (cnt ? atomicAdd(&bcnt[t], cnt) : 0);
        }
        __syncthreads();
        for (int e = tid; e < EDGES_PER_BINA; e += 256) {
            int2 p = *(const int2*)&ei[2 * (base + e)];
            int bkt = p.y >> 6;
            int pos = atomicAdd(&cursor[bkt], 1);
            if (pos < (bkt + 1) * BUCKET_CAP)  // overflow guard (never fires at +8 sigma)
                bucketed[pos] = ((unsigned)(p.y & 63) << 16) | (unsigned)p.x;
        }
    } else if (b < BINA_BLOCKS + CONV_BLOCKS) {
        int t = (b - BINA_BLOCKS) * 256 + tid;
        int base = t * 8;
        float4 a = *(const float4*)&x[base];
        float4 c = *(const float4*)&x[base + 4];
        ushort8_t o;
        o[0] = f2bf(a.x); o[1] = f2bf(a.y); o[2] = f2bf(a.z); o[3] = f2bf(a.w);
        o[4] = f2bf(c.x); o[5] = f2bf(c.y); o[6] = f2bf(c.z); o[7] = f2bf(c.w);
        *(ushort8_t*)&xb[base] = o;
    } else {
        int t = (b - BINA_BLOCKS - CONV_BLOCKS) * 256 + tid;
        int base = t * 8;
        float4 a = *(const float4*)&W[base];
        float4 c = *(const float4*)&W[base + 4];
        ushort8_t h, l;
        h[0] = f2bf(a.x); h[1] = f2bf(a.y); h[2] = f2bf(a.z); h[3] = f2bf(a.w);
        h[4] = f2bf(c.x); h[5] = f2bf(c.y); h[6] = f2bf(c.z); h[7] = f2bf(c.w);
        l[0] = f2bf(a.x - bf2f(h[0])); l[1] = f2bf(a.y - bf2f(h[1]));
        l[2] = f2bf(a.z - bf2f(h[2])); l[3] = f2bf(a.w - bf2f(h[3]));
        l[4] = f2bf(c.x - bf2f(h[4])); l[5] = f2bf(c.y - bf2f(h[5]));
        l[6] = f2bf(c.z - bf2f(h[6])); l[7] = f2bf(c.w - bf2f(h[7]));
        *(ushort8_t*)&Wh[base] = h;
        *(ushort8_t*)&Wl[base] = l;
    }
}

// ---- aggregate (fused bin-to-node): block = 64-node bucket, 512 threads ----
// Stage 1: wave-0 shfl-scan of the 64 node counts -> per-node LDS offsets.
// Stage 2: scatter bucket edges into LDS lsrc (per-node order via LDS cursors).
// Stage 3: wave per node: y[i] = di*(di*x[i] + sum_s rsqrt(deg_s)*x[s]), di inline.

__global__ __launch_bounds__(512) void k_aggregate(
        const unsigned* __restrict__ xbu, const int* __restrict__ counts,
        const int* __restrict__ bcnt, const unsigned* __restrict__ bucketed,
        unsigned* __restrict__ yh, unsigned* __restrict__ yl) {
    __shared__ int lsrc[BUCKET_CAP];
    __shared__ int ncnt[64], nstart[64], ncur[64];
    int b = blockIdx.x, tid = threadIdx.x;
    int node0 = b << 6;
    if (tid < 64) {                            // wave 0: 64-wide inclusive shfl-scan
        int n = node0 + tid;
        int c = (n < N_NODES) ? counts[n] : 0;
        ncnt[tid] = c;
        int v = c;
        #pragma unroll
        for (int off = 1; off < 64; off <<= 1) {
            int u = __shfl_up(v, off);
            if (tid >= off) v += u;
        }
        nstart[tid] = v;                       // inclusive end
        ncur[tid] = v - c;                     // exclusive start cursor
    }
    __syncthreads();
    int ecnt = bcnt[b]; if (ecnt > BUCKET_CAP) ecnt = BUCKET_CAP;
    const unsigned* bb = bucketed + b * BUCKET_CAP;
    for (int e = tid; e < ecnt; e += 512) {
        unsigned p = bb[e];
        int pos = atomicAdd(&ncur[p >> 16], 1);
        lsrc[pos] = (int)(p & 0xffffu);
    }
    __syncthreads();
    int wv = tid >> 6, lane = tid & 63;
    for (int k = 0; k < 8; ++k) {
        int ln = wv * 8 + k;
        int i = node0 + ln;
        if (i >= N_NODES) break;
        int cnt = ncnt[ln];
        float di = rsqrtf((float)(cnt + 1));
        int end = nstart[ln];
        int start = end - cnt;
        unsigned pself = xbu[i * 64 + lane];
        float sx = di * blo(pself), sy = di * bhi(pself);     // self-loop term
        for (int e0 = start; e0 < end; e0 += 64) {
            int ne = end - e0; if (ne > 64) ne = 64;
            int s = 0; float w = 0.f;
            if (lane < ne) {
                s = lsrc[e0 + lane];
                w = rsqrtf((float)(counts[s] + 1));
            }
            int t = 0;
            for (; t + 8 <= ne; t += 8) {
                int s0 = __shfl(s, t),     s1 = __shfl(s, t + 1);
                int s2 = __shfl(s, t + 2), s3 = __shfl(s, t + 3);
                int s4 = __shfl(s, t + 4), s5 = __shfl(s, t + 5);
                int s6 = __shfl(s, t + 6), s7 = __shfl(s, t + 7);
                float w0 = __shfl(w, t),     w1 = __shfl(w, t + 1);
                float w2 = __shfl(w, t + 2), w3 = __shfl(w, t + 3);
                float w4 = __shfl(w, t + 4), w5 = __shfl(w, t + 5);
                float w6 = __shfl(w, t + 6), w7 = __shfl(w, t + 7);
                unsigned p0 = xbu[s0 * 64 + lane], p1 = xbu[s1 * 64 + lane];
                unsigned p2 = xbu[s2 * 64 + lane], p3 = xbu[s3 * 64 + lane];
                unsigned p4 = xbu[s4 * 64 + lane], p5 = xbu[s5 * 64 + lane];
                unsigned p6 = xbu[s6 * 64 + lane], p7 = xbu[s7 * 64 + lane];
                sx += w0 * blo(p0) + w1 * blo(p1) + w2 * blo(p2) + w3 * blo(p3)
                    + w4 * blo(p4) + w5 * blo(p5) + w6 * blo(p6) + w7 * blo(p7);
                sy += w0 * bhi(p0) + w1 * bhi(p1) + w2 * bhi(p2) + w3 * bhi(p3)
                    + w4 * bhi(p4) + w5 * bhi(p5) + w6 * bhi(p6) + w7 * bhi(p7);
            }
            for (; t < ne; ++t) {
                int st = __shfl(s, t); float wt = __shfl(w, t);
                unsigned p = xbu[st * 64 + lane];
                sx += wt * blo(p); sy += wt * bhi(p);
            }
        }
        float vx = di * sx, vy = di * sy;
        unsigned short hx = f2bf(vx), hy = f2bf(vy);
        unsigned short lx = f2bf(vx - bf2f(hx)), ly = f2bf(vy - bf2f(hy));
        yh[i * 64 + lane] = (unsigned)hx | ((unsigned)hy << 16);
        yl[i * 64 + lane] = (unsigned)lx | ((unsigned)ly << 16);
    }
}

// ------- GEMM: out = relu(y @ W^T + b), split-bf16 MFMA, pre-converted inputs -------

#define LDK 136   // LDS K-stride (ushorts): 272B rows -> b128-aligned, bank-uniform frags

__global__ __launch_bounds__(256) void k_gemm(
        const unsigned short* __restrict__ yh, const unsigned short* __restrict__ yl,
        const unsigned short* __restrict__ Wh, const unsigned short* __restrict__ Wl,
        const float* __restrict__ bias, float* __restrict__ out) {
    __shared__ unsigned short Ah[64 * LDK], Al[64 * LDK];
    int tid = threadIdx.x;
    int lane = tid & 63;
    int wv = tid >> 6;
    int jb = blockIdx.x * 64;        // n fastest-varying -> y-tile reuse in L2
    int i0 = blockIdx.y * 64;
    int n0 = wv * 16;
    int rl = lane & 15;              // m (A) / n (B) within 16-tile
    int quad = lane >> 4;

    bf16x8 bh[4], bl[4];
    #pragma unroll
    for (int ks = 0; ks < 4; ++ks) {
        int off = (jb + n0 + rl) * IN_DIM + ks * 32 + quad * 8;
        bh[ks] = *(const bf16x8*)&Wh[off];
        bl[ks] = *(const bf16x8*)&Wl[off];
    }

    #pragma unroll
    for (int it = 0; it < 4; ++it) {
        int g = it * 256 + tid;      // 0..1023
        int r = g >> 4;              // 0..63
        int c8 = g & 15;             // ushort8 chunk along k
        int row = i0 + r; if (row >= N_NODES) row = N_NODES - 1;
        int ga = row * IN_DIM + c8 * 8;
        int la = r * LDK + c8 * 8;
        *(bf16x8*)&Ah[la] = *(const bf16x8*)&yh[ga];
        *(bf16x8*)&Al[la] = *(const bf16x8*)&yl[ga];
    }
    __syncthreads();

    f32x4 acc[4] = {{0.f,0.f,0.f,0.f},{0.f,0.f,0.f,0.f},{0.f,0.f,0.f,0.f},{0.f,0.f,0.f,0.f}};
    #pragma unroll
    for (int ks = 0; ks < 4; ++ks) {
        int koff = ks * 32 + quad * 8;
        #pragma unroll
        for (int mt = 0; mt < 4; ++mt) {
            bf16x8 ah = *(bf16x8*)&Ah[(mt * 16 + rl) * LDK + koff];
            bf16x8 al = *(bf16x8*)&Al[(mt * 16 + rl) * LDK + koff];
            acc[mt] = __builtin_amdgcn_mfma_f32_16x16x32_bf16(ah, bh[ks], acc[mt], 0, 0, 0);
            acc[mt] = __builtin_amdgcn_mfma_f32_16x16x32_bf16(ah, bl[ks], acc[mt], 0, 0, 0);
            acc[mt] = __builtin_amdgcn_mfma_f32_16x16x32_bf16(al, bh[ks], acc[mt], 0, 0, 0);
        }
    }

    float bv = bias[jb + n0 + rl];
    #pragma unroll
    for (int mt = 0; mt < 4; ++mt) {
        #pragma unroll
        for (int r = 0; r < 4; ++r) {
            int row = i0 + mt * 16 + quad * 4 + r;
            if (row < N_NODES) {
                float v = acc[mt][r] + bv;
                out[row * OUT_DIM + jb + n0 + rl] = fmaxf(v, 0.f);
            }
        }
    }
}

// ---------------- launch ----------------

extern "C" void kernel_launch(void* const* d_in, const int* in_sizes, int n_in,
                              void* d_out, int out_size, void* d_ws, size_t ws_size,
                              hipStream_t stream) {
    const float* x  = (const float*)d_in[0];
    const int*   ei = (const int*)d_in[1];
    const float* W  = (const float*)d_in[2];
    const float* b  = (const float*)d_in[3];
    float* out = (float*)d_out;

    char* ws = (char*)d_ws;
    int*            counts   = (int*)(ws + 0);                   // 50000 ints
    int*            bcnt     = (int*)(ws + 200704);              // 782 ints
    unsigned*       bucketed = (unsigned*)(ws + 204800);         // 782*1280 u32 (4.0 MB)
    unsigned*       yh       = (unsigned*)(ws + 4208640);        // 12.8 MB
    unsigned*       yl       = (unsigned*)(ws + 17008640);       // 12.8 MB
    unsigned short* xb       = (unsigned short*)(ws + 29808640); // 12.8 MB
    unsigned short* Wh       = (unsigned short*)(ws + 42608640); // 64 KB
    unsigned short* Wl       = (unsigned short*)(ws + 42674176); // 64 KB

    hipMemsetAsync(counts, 0, 203832, stream);                   // counts + bcnt

    k_prep<<<BINA_BLOCKS + CONV_BLOCKS + WCONV_BLOCKS, 256, 0, stream>>>(
        ei, counts, bcnt, bucketed, x, xb, W, Wh, Wl);
    k_aggregate<<<N_BUCKETS, 512, 0, stream>>>((const unsigned*)xb, counts, bcnt,
                                               bucketed, yh, yl);
    dim3 g(OUT_DIM / 64, (N_NODES + 63) / 64);
    k_gemm<<<g, 256, 0, stream>>>((const unsigned short*)yh, (const unsigned short*)yl,
                                  Wh, Wl, b, out);
}

// Round 8
// 197.774 us; speedup vs baseline: 1.7870x; 1.0281x over previous
//
#include <hip/hip_runtime.h>

#define N_NODES 50000
#define IN_DIM  128
#define OUT_DIM 256
#define N_EDGES 800000
#define BINA_BLOCKS 128    // 6250 edges each (exact)
#define EDGES_PER_BINA 6250
#define XCONV_BLOCKS 782   // ceil(6400000/(1024*8))
#define WCONV_BLOCKS 4     // 32768/(1024*8)
#define N_BUCKETS 782      // 64-node ranges (ceil(50000/64))
#define BUCKET_CAP 1280    // mean 1024, sd ~32 -> +8 sigma margin

typedef short bf16x8 __attribute__((ext_vector_type(8)));   // 8 bf16 = 4 VGPRs
typedef float f32x4  __attribute__((ext_vector_type(4)));   // MFMA acc
typedef unsigned short ushort8_t __attribute__((ext_vector_type(8)));

__device__ __forceinline__ unsigned short f2bf(float f) {
    unsigned u = __float_as_uint(f);
    return (unsigned short)((u + 0x7fffu + ((u >> 16) & 1u)) >> 16);
}
__device__ __forceinline__ float bf2f(unsigned short h) {
    return __uint_as_float(((unsigned)h) << 16);
}
__device__ __forceinline__ float blo(unsigned p) { return __uint_as_float(p << 16); }
__device__ __forceinline__ float bhi(unsigned p) { return __uint_as_float(p & 0xffff0000u); }

// ---- fused prep (1024-thread blocks): [binA] | [x->bf16] | [W->split-bf16] ----
// binA blocks first: they're the long pole, 16 waves each for latency hiding.
// pack = (dst&63)<<16 | src   (src < 2^16 since N_NODES=50000, local < 2^6)

__global__ __launch_bounds__(1024) void k_prep(const int* __restrict__ ei,
                                               int* __restrict__ counts,
                                               int* __restrict__ bcnt,
                                               unsigned* __restrict__ bucketed,
                                               const float* __restrict__ x,
                                               unsigned short* __restrict__ xb,
                                               const float* __restrict__ W,
                                               unsigned short* __restrict__ Wh,
                                               unsigned short* __restrict__ Wl) {
    __shared__ int hist[N_BUCKETS];
    __shared__ int cursor[N_BUCKETS];
    int b = blockIdx.x, tid = threadIdx.x;
    if (b < BINA_BLOCKS) {
        int base = b * EDGES_PER_BINA;
        for (int t = tid; t < N_BUCKETS; t += 1024) hist[t] = 0;
        __syncthreads();
        for (int e = tid; e < EDGES_PER_BINA; e += 1024) {
            int2 p = *(const int2*)&ei[2 * (base + e)];
            atomicAdd(&counts[p.y], 1);        // global deg histogram
            atomicAdd(&hist[p.y >> 6], 1);     // LDS bucket histogram
        }
        __syncthreads();
        for (int t = tid; t < N_BUCKETS; t += 1024) {
            int cnt = hist[t];
            cursor[t] = t * BUCKET_CAP + (cnt ? atomicAdd(&bcnt[t], cnt) : 0);
        }
        __syncthreads();
        for (int e = tid; e < EDGES_PER_BINA; e += 1024) {
            int2 p = *(const int2*)&ei[2 * (base + e)];
            int bkt = p.y >> 6;
            int pos = atomicAdd(&cursor[bkt], 1);
            if (pos < (bkt + 1) * BUCKET_CAP)  // overflow guard (never fires at +8 sigma)
                bucketed[pos] = ((unsigned)(p.y & 63) << 16) | (unsigned)p.x;
        }
    } else if (b < BINA_BLOCKS + XCONV_BLOCKS) {
        int t = (b - BINA_BLOCKS) * 1024 + tid;
        if (t < N_NODES * IN_DIM / 8) {
            int base = t * 8;
            float4 a = *(const float4*)&x[base];
            float4 c = *(const float4*)&x[base + 4];
            ushort8_t o;
            o[0] = f2bf(a.x); o[1] = f2bf(a.y); o[2] = f2bf(a.z); o[3] = f2bf(a.w);
            o[4] = f2bf(c.x); o[5] = f2bf(c.y); o[6] = f2bf(c.z); o[7] = f2bf(c.w);
            *(ushort8_t*)&xb[base] = o;
        }
    } else {
        int t = (b - BINA_BLOCKS - XCONV_BLOCKS) * 1024 + tid;
        int base = t * 8;
        float4 a = *(const float4*)&W[base];
        float4 c = *(const float4*)&W[base + 4];
        ushort8_t h, l;
        h[0] = f2bf(a.x); h[1] = f2bf(a.y); h[2] = f2bf(a.z); h[3] = f2bf(a.w);
        h[4] = f2bf(c.x); h[5] = f2bf(c.y); h[6] = f2bf(c.z); h[7] = f2bf(c.w);
        l[0] = f2bf(a.x - bf2f(h[0])); l[1] = f2bf(a.y - bf2f(h[1]));
        l[2] = f2bf(a.z - bf2f(h[2])); l[3] = f2bf(a.w - bf2f(h[3]));
        l[4] = f2bf(c.x - bf2f(h[4])); l[5] = f2bf(c.y - bf2f(h[5]));
        l[6] = f2bf(c.z - bf2f(h[6])); l[7] = f2bf(c.w - bf2f(h[7]));
        *(ushort8_t*)&Wh[base] = h;
        *(ushort8_t*)&Wl[base] = l;
    }
}

// ---- aggregate (fused bin-to-node): block = 64-node bucket, 512 threads ----

__global__ __launch_bounds__(512) void k_aggregate(
        const unsigned* __restrict__ xbu, const int* __restrict__ counts,
        const int* __restrict__ bcnt, const unsigned* __restrict__ bucketed,
        unsigned* __restrict__ yh, unsigned* __restrict__ yl) {
    __shared__ int lsrc[BUCKET_CAP];
    __shared__ int ncnt[64], nstart[64], ncur[64];
    int b = blockIdx.x, tid = threadIdx.x;
    int node0 = b << 6;
    if (tid < 64) {                            // wave 0: 64-wide inclusive shfl-scan
        int n = node0 + tid;
        int c = (n < N_NODES) ? counts[n] : 0;
        ncnt[tid] = c;
        int v = c;
        #pragma unroll
        for (int off = 1; off < 64; off <<= 1) {
            int u = __shfl_up(v, off);
            if (tid >= off) v += u;
        }
        nstart[tid] = v;                       // inclusive end
        ncur[tid] = v - c;                     // exclusive start cursor
    }
    __syncthreads();
    int ecnt = bcnt[b]; if (ecnt > BUCKET_CAP) ecnt = BUCKET_CAP;
    const unsigned* bb = bucketed + b * BUCKET_CAP;
    for (int e = tid; e < ecnt; e += 512) {
        unsigned p = bb[e];
        int pos = atomicAdd(&ncur[p >> 16], 1);
        lsrc[pos] = (int)(p & 0xffffu);
    }
    __syncthreads();
    int wv = tid >> 6, lane = tid & 63;
    for (int k = 0; k < 8; ++k) {
        int ln = wv * 8 + k;
        int i = node0 + ln;
        if (i >= N_NODES) break;
        int cnt = ncnt[ln];
        float di = rsqrtf((float)(cnt + 1));
        int end = nstart[ln];
        int start = end - cnt;
        unsigned pself = xbu[i * 64 + lane];
        float sx = di * blo(pself), sy = di * bhi(pself);     // self-loop term
        for (int e0 = start; e0 < end; e0 += 64) {
            int ne = end - e0; if (ne > 64) ne = 64;
            int s = 0; float w = 0.f;
            if (lane < ne) {
                s = lsrc[e0 + lane];
                w = rsqrtf((float)(counts[s] + 1));
            }
            int t = 0;
            for (; t + 8 <= ne; t += 8) {
                int s0 = __shfl(s, t),     s1 = __shfl(s, t + 1);
                int s2 = __shfl(s, t + 2), s3 = __shfl(s, t + 3);
                int s4 = __shfl(s, t + 4), s5 = __shfl(s, t + 5);
                int s6 = __shfl(s, t + 6), s7 = __shfl(s, t + 7);
                float w0 = __shfl(w, t),     w1 = __shfl(w, t + 1);
                float w2 = __shfl(w, t + 2), w3 = __shfl(w, t + 3);
                float w4 = __shfl(w, t + 4), w5 = __shfl(w, t + 5);
                float w6 = __shfl(w, t + 6), w7 = __shfl(w, t + 7);
                unsigned p0 = xbu[s0 * 64 + lane], p1 = xbu[s1 * 64 + lane];
                unsigned p2 = xbu[s2 * 64 + lane], p3 = xbu[s3 * 64 + lane];
                unsigned p4 = xbu[s4 * 64 + lane], p5 = xbu[s5 * 64 + lane];
                unsigned p6 = xbu[s6 * 64 + lane], p7 = xbu[s7 * 64 + lane];
                sx += w0 * blo(p0) + w1 * blo(p1) + w2 * blo(p2) + w3 * blo(p3)
                    + w4 * blo(p4) + w5 * blo(p5) + w6 * blo(p6) + w7 * blo(p7);
                sy += w0 * bhi(p0) + w1 * bhi(p1) + w2 * bhi(p2) + w3 * bhi(p3)
                    + w4 * bhi(p4) + w5 * bhi(p5) + w6 * bhi(p6) + w7 * bhi(p7);
            }
            for (; t < ne; ++t) {
                int st = __shfl(s, t); float wt = __shfl(w, t);
                unsigned p = xbu[st * 64 + lane];
                sx += wt * blo(p); sy += wt * bhi(p);
            }
        }
        float vx = di * sx, vy = di * sy;
        unsigned short hx = f2bf(vx), hy = f2bf(vy);
        unsigned short lx = f2bf(vx - bf2f(hx)), ly = f2bf(vy - bf2f(hy));
        yh[i * 64 + lane] = (unsigned)hx | ((unsigned)hy << 16);
        yl[i * 64 + lane] = (unsigned)lx | ((unsigned)ly << 16);
    }
}

// ------- GEMM: out = relu(y @ W^T + b), split-bf16 MFMA, pre-converted inputs -------

#define LDK 136   // LDS K-stride (ushorts): 272B rows -> b128-aligned, bank-uniform frags

__global__ __launch_bounds__(256) void k_gemm(
        const unsigned short* __restrict__ yh, const unsigned short* __restrict__ yl,
        const unsigned short* __restrict__ Wh, const unsigned short* __restrict__ Wl,
        const float* __restrict__ bias, float* __restrict__ out) {
    __shared__ unsigned short Ah[64 * LDK], Al[64 * LDK];
    int tid = threadIdx.x;
    int lane = tid & 63;
    int wv = tid >> 6;
    int jb = blockIdx.x * 64;        // n fastest-varying -> y-tile reuse in L2
    int i0 = blockIdx.y * 64;
    int n0 = wv * 16;
    int rl = lane & 15;              // m (A) / n (B) within 16-tile
    int quad = lane >> 4;

    bf16x8 bh[4], bl[4];
    #pragma unroll
    for (int ks = 0; ks < 4; ++ks) {
        int off = (jb + n0 + rl) * IN_DIM + ks * 32 + quad * 8;
        bh[ks] = *(const bf16x8*)&Wh[off];
        bl[ks] = *(const bf16x8*)&Wl[off];
    }

    #pragma unroll
    for (int it = 0; it < 4; ++it) {
        int g = it * 256 + tid;      // 0..1023
        int r = g >> 4;              // 0..63
        int c8 = g & 15;             // ushort8 chunk along k
        int row = i0 + r; if (row >= N_NODES) row = N_NODES - 1;
        int ga = row * IN_DIM + c8 * 8;
        int la = r * LDK + c8 * 8;
        *(bf16x8*)&Ah[la] = *(const bf16x8*)&yh[ga];
        *(bf16x8*)&Al[la] = *(const bf16x8*)&yl[ga];
    }
    __syncthreads();

    f32x4 acc[4] = {{0.f,0.f,0.f,0.f},{0.f,0.f,0.f,0.f},{0.f,0.f,0.f,0.f},{0.f,0.f,0.f,0.f}};
    #pragma unroll
    for (int ks = 0; ks < 4; ++ks) {
        int koff = ks * 32 + quad * 8;
        #pragma unroll
        for (int mt = 0; mt < 4; ++mt) {
            bf16x8 ah = *(bf16x8*)&Ah[(mt * 16 + rl) * LDK + koff];
            bf16x8 al = *(bf16x8*)&Al[(mt * 16 + rl) * LDK + koff];
            acc[mt] = __builtin_amdgcn_mfma_f32_16x16x32_bf16(ah, bh[ks], acc[mt], 0, 0, 0);
            acc[mt] = __builtin_amdgcn_mfma_f32_16x16x32_bf16(ah, bl[ks], acc[mt], 0, 0, 0);
            acc[mt] = __builtin_amdgcn_mfma_f32_16x16x32_bf16(al, bh[ks], acc[mt], 0, 0, 0);
        }
    }

    float bv = bias[jb + n0 + rl];
    #pragma unroll
    for (int mt = 0; mt < 4; ++mt) {
        #pragma unroll
        for (int r = 0; r < 4; ++r) {
            int row = i0 + mt * 16 + quad * 4 + r;
            if (row < N_NODES) {
                float v = acc[mt][r] + bv;
                out[row * OUT_DIM + jb + n0 + rl] = fmaxf(v, 0.f);
            }
        }
    }
}

// ---------------- launch ----------------

extern "C" void kernel_launch(void* const* d_in, const int* in_sizes, int n_in,
                              void* d_out, int out_size, void* d_ws, size_t ws_size,
                              hipStream_t stream) {
    const float* x  = (const float*)d_in[0];
    const int*   ei = (const int*)d_in[1];
    const float* W  = (const float*)d_in[2];
    const float* b  = (const float*)d_in[3];
    float* out = (float*)d_out;

    char* ws = (char*)d_ws;
    int*            counts   = (int*)(ws + 0);                   // 50000 ints
    int*            bcnt     = (int*)(ws + 200704);              // 782 ints
    unsigned*       bucketed = (unsigned*)(ws + 204800);         // 782*1280 u32 (4.0 MB)
    unsigned*       yh       = (unsigned*)(ws + 4208640);        // 12.8 MB
    unsigned*       yl       = (unsigned*)(ws + 17008640);       // 12.8 MB
    unsigned short* xb       = (unsigned short*)(ws + 29808640); // 12.8 MB
    unsigned short* Wh       = (unsigned short*)(ws + 42608640); // 64 KB
    unsigned short* Wl       = (unsigned short*)(ws + 42674176); // 64 KB

    hipMemsetAsync(counts, 0, 203832, stream);                   // counts + bcnt

    k_prep<<<BINA_BLOCKS + XCONV_BLOCKS + WCONV_BLOCKS, 1024, 0, stream>>>(
        ei, counts, bcnt, bucketed, x, xb, W, Wh, Wl);
    k_aggregate<<<N_BUCKETS, 512, 0, stream>>>((const unsigned*)xb, counts, bcnt,
                                               bucketed, yh, yl);
    dim3 g(OUT_DIM / 64, (N_NODES + 63) / 64);
    k_gemm<<<g, 256, 0, stream>>>((const unsigned short*)yh, (const unsigned short*)yl,
                                  Wh, Wl, b, out);
}

// Round 9
// 172.479 us; speedup vs baseline: 2.0491x; 1.1467x over previous
//
#include <hip/hip_runtime.h>

#define N_NODES 50000
#define IN_DIM  128
#define OUT_DIM 256
#define N_EDGES 800000
#define BINA_BLOCKS 128    // 6250 edges each (exact)
#define EDGES_PER_BINA 6250
#define XCONV_BLOCKS 782   // ceil(6400000/(1024*8))
#define WCONV_BLOCKS 4     // 32768/(1024*8)
#define N_BUCKETS 782      // 64-node ranges (ceil(50000/64))
#define BUCKET_CAP 1280    // mean 1024, sd ~32 -> +8 sigma margin

typedef short bf16x8 __attribute__((ext_vector_type(8)));   // 8 bf16 = 4 VGPRs
typedef float f32x4  __attribute__((ext_vector_type(4)));   // MFMA acc
typedef unsigned short ushort8_t __attribute__((ext_vector_type(8)));

__device__ __forceinline__ unsigned short f2bf(float f) {
    unsigned u = __float_as_uint(f);
    return (unsigned short)((u + 0x7fffu + ((u >> 16) & 1u)) >> 16);
}
__device__ __forceinline__ float bf2f(unsigned short h) {
    return __uint_as_float(((unsigned)h) << 16);
}
__device__ __forceinline__ float blo(unsigned p) { return __uint_as_float(p << 16); }
__device__ __forceinline__ float bhi(unsigned p) { return __uint_as_float(p & 0xffff0000u); }

// ---- fused prep (1024-thread blocks): [binA] | [x->bf16] | [W->split-bf16] ----
// binA: NO global atomics (degree derived later from bucketed data by k_degree).
// pack = (dst&63)<<16 | src   (src < 2^16 since N_NODES=50000, local < 2^6)

__global__ __launch_bounds__(1024) void k_prep(const int* __restrict__ ei,
                                               int* __restrict__ bcnt,
                                               unsigned* __restrict__ bucketed,
                                               const float* __restrict__ x,
                                               unsigned short* __restrict__ xb,
                                               const float* __restrict__ W,
                                               unsigned short* __restrict__ Wh,
                                               unsigned short* __restrict__ Wl) {
    __shared__ int hist[N_BUCKETS];
    __shared__ int cursor[N_BUCKETS];
    int b = blockIdx.x, tid = threadIdx.x;
    if (b < BINA_BLOCKS) {
        int base = b * EDGES_PER_BINA;
        for (int t = tid; t < N_BUCKETS; t += 1024) hist[t] = 0;
        __syncthreads();
        for (int e = tid; e < EDGES_PER_BINA; e += 1024) {
            int2 p = *(const int2*)&ei[2 * (base + e)];
            atomicAdd(&hist[p.y >> 6], 1);     // LDS bucket histogram only
        }
        __syncthreads();
        for (int t = tid; t < N_BUCKETS; t += 1024) {
            int cnt = hist[t];
            cursor[t] = t * BUCKET_CAP + (cnt ? atomicAdd(&bcnt[t], cnt) : 0);
        }
        __syncthreads();
        for (int e = tid; e < EDGES_PER_BINA; e += 1024) {
            int2 p = *(const int2*)&ei[2 * (base + e)];
            int bkt = p.y >> 6;
            int pos = atomicAdd(&cursor[bkt], 1);
            if (pos < (bkt + 1) * BUCKET_CAP)  // overflow guard (never fires at +8 sigma)
                bucketed[pos] = ((unsigned)(p.y & 63) << 16) | (unsigned)p.x;
        }
    } else if (b < BINA_BLOCKS + XCONV_BLOCKS) {
        int t = (b - BINA_BLOCKS) * 1024 + tid;
        if (t < N_NODES * IN_DIM / 8) {
            int base = t * 8;
            float4 a = *(const float4*)&x[base];
            float4 c = *(const float4*)&x[base + 4];
            ushort8_t o;
            o[0] = f2bf(a.x); o[1] = f2bf(a.y); o[2] = f2bf(a.z); o[3] = f2bf(a.w);
            o[4] = f2bf(c.x); o[5] = f2bf(c.y); o[6] = f2bf(c.z); o[7] = f2bf(c.w);
            *(ushort8_t*)&xb[base] = o;
        }
    } else {
        int t = (b - BINA_BLOCKS - XCONV_BLOCKS) * 1024 + tid;
        int base = t * 8;
        float4 a = *(const float4*)&W[base];
        float4 c = *(const float4*)&W[base + 4];
        ushort8_t h, l;
        h[0] = f2bf(a.x); h[1] = f2bf(a.y); h[2] = f2bf(a.z); h[3] = f2bf(a.w);
        h[4] = f2bf(c.x); h[5] = f2bf(c.y); h[6] = f2bf(c.z); h[7] = f2bf(c.w);
        l[0] = f2bf(a.x - bf2f(h[0])); l[1] = f2bf(a.y - bf2f(h[1]));
        l[2] = f2bf(a.z - bf2f(h[2])); l[3] = f2bf(a.w - bf2f(h[3]));
        l[4] = f2bf(c.x - bf2f(h[4])); l[5] = f2bf(c.y - bf2f(h[5]));
        l[6] = f2bf(c.z - bf2f(h[6])); l[7] = f2bf(c.w - bf2f(h[7]));
        *(ushort8_t*)&Wh[base] = h;
        *(ushort8_t*)&Wl[base] = l;
    }
}

// ---- degree from bucketed data: bucket b owns nodes [64b, 64b+64) ----
// Replaces 800K random global atomics with L2-warm coalesced reads + LDS hist.

__global__ __launch_bounds__(256) void k_degree(const int* __restrict__ bcnt,
                                                const unsigned* __restrict__ bucketed,
                                                int* __restrict__ counts) {
    __shared__ int h[64];
    int b = blockIdx.x, tid = threadIdx.x;
    if (tid < 64) h[tid] = 0;
    __syncthreads();
    int ecnt = bcnt[b]; if (ecnt > BUCKET_CAP) ecnt = BUCKET_CAP;
    const unsigned* bb = bucketed + b * BUCKET_CAP;
    for (int e = tid; e < ecnt; e += 256)
        atomicAdd(&h[bb[e] >> 16], 1);
    __syncthreads();
    int n = (b << 6) + tid;
    if (tid < 64 && n < N_NODES) counts[n] = h[tid];
}

// ---- aggregate (fused bin-to-node): block = 64-node bucket, 512 threads ----

__global__ __launch_bounds__(512) void k_aggregate(
        const unsigned* __restrict__ xbu, const int* __restrict__ counts,
        const int* __restrict__ bcnt, const unsigned* __restrict__ bucketed,
        unsigned* __restrict__ yh, unsigned* __restrict__ yl) {
    __shared__ int lsrc[BUCKET_CAP];
    __shared__ int ncnt[64], nstart[64], ncur[64];
    int b = blockIdx.x, tid = threadIdx.x;
    int node0 = b << 6;
    if (tid < 64) {                            // wave 0: 64-wide inclusive shfl-scan
        int n = node0 + tid;
        int c = (n < N_NODES) ? counts[n] : 0;
        ncnt[tid] = c;
        int v = c;
        #pragma unroll
        for (int off = 1; off < 64; off <<= 1) {
            int u = __shfl_up(v, off);
            if (tid >= off) v += u;
        }
        nstart[tid] = v;                       // inclusive end
        ncur[tid] = v - c;                     // exclusive start cursor
    }
    __syncthreads();
    int ecnt = bcnt[b]; if (ecnt > BUCKET_CAP) ecnt = BUCKET_CAP;
    const unsigned* bb = bucketed + b * BUCKET_CAP;
    for (int e = tid; e < ecnt; e += 512) {
        unsigned p = bb[e];
        int pos = atomicAdd(&ncur[p >> 16], 1);
        lsrc[pos] = (int)(p & 0xffffu);
    }
    __syncthreads();
    int wv = tid >> 6, lane = tid & 63;
    for (int k = 0; k < 8; ++k) {
        int ln = wv * 8 + k;
        int i = node0 + ln;
        if (i >= N_NODES) break;
        int cnt = ncnt[ln];
        float di = rsqrtf((float)(cnt + 1));
        int end = nstart[ln];
        int start = end - cnt;
        unsigned pself = xbu[i * 64 + lane];
        float sx = di * blo(pself), sy = di * bhi(pself);     // self-loop term
        for (int e0 = start; e0 < end; e0 += 64) {
            int ne = end - e0; if (ne > 64) ne = 64;
            int s = 0; float w = 0.f;
            if (lane < ne) {
                s = lsrc[e0 + lane];
                w = rsqrtf((float)(counts[s] + 1));
            }
            int t = 0;
            for (; t + 8 <= ne; t += 8) {
                int s0 = __shfl(s, t),     s1 = __shfl(s, t + 1);
                int s2 = __shfl(s, t + 2), s3 = __shfl(s, t + 3);
                int s4 = __shfl(s, t + 4), s5 = __shfl(s, t + 5);
                int s6 = __shfl(s, t + 6), s7 = __shfl(s, t + 7);
                float w0 = __shfl(w, t),     w1 = __shfl(w, t + 1);
                float w2 = __shfl(w, t + 2), w3 = __shfl(w, t + 3);
                float w4 = __shfl(w, t + 4), w5 = __shfl(w, t + 5);
                float w6 = __shfl(w, t + 6), w7 = __shfl(w, t + 7);
                unsigned p0 = xbu[s0 * 64 + lane], p1 = xbu[s1 * 64 + lane];
                unsigned p2 = xbu[s2 * 64 + lane], p3 = xbu[s3 * 64 + lane];
                unsigned p4 = xbu[s4 * 64 + lane], p5 = xbu[s5 * 64 + lane];
                unsigned p6 = xbu[s6 * 64 + lane], p7 = xbu[s7 * 64 + lane];
                sx += w0 * blo(p0) + w1 * blo(p1) + w2 * blo(p2) + w3 * blo(p3)
                    + w4 * blo(p4) + w5 * blo(p5) + w6 * blo(p6) + w7 * blo(p7);
                sy += w0 * bhi(p0) + w1 * bhi(p1) + w2 * bhi(p2) + w3 * bhi(p3)
                    + w4 * bhi(p4) + w5 * bhi(p5) + w6 * bhi(p6) + w7 * bhi(p7);
            }
            for (; t < ne; ++t) {
                int st = __shfl(s, t); float wt = __shfl(w, t);
                unsigned p = xbu[st * 64 + lane];
                sx += wt * blo(p); sy += wt * bhi(p);
            }
        }
        float vx = di * sx, vy = di * sy;
        unsigned short hx = f2bf(vx), hy = f2bf(vy);
        unsigned short lx = f2bf(vx - bf2f(hx)), ly = f2bf(vy - bf2f(hy));
        yh[i * 64 + lane] = (unsigned)hx | ((unsigned)hy << 16);
        yl[i * 64 + lane] = (unsigned)lx | ((unsigned)ly << 16);
    }
}

// ------- GEMM: out = relu(y @ W^T + b), split-bf16 MFMA, pre-converted inputs -------

#define LDK 136   // LDS K-stride (ushorts): 272B rows -> b128-aligned, bank-uniform frags

__global__ __launch_bounds__(256) void k_gemm(
        const unsigned short* __restrict__ yh, const unsigned short* __restrict__ yl,
        const unsigned short* __restrict__ Wh, const unsigned short* __restrict__ Wl,
        const float* __restrict__ bias, float* __restrict__ out) {
    __shared__ unsigned short Ah[64 * LDK], Al[64 * LDK];
    int tid = threadIdx.x;
    int lane = tid & 63;
    int wv = tid >> 6;
    int jb = blockIdx.x * 64;        // n fastest-varying -> y-tile reuse in L2
    int i0 = blockIdx.y * 64;
    int n0 = wv * 16;
    int rl = lane & 15;              // m (A) / n (B) within 16-tile
    int quad = lane >> 4;

    bf16x8 bh[4], bl[4];
    #pragma unroll
    for (int ks = 0; ks < 4; ++ks) {
        int off = (jb + n0 + rl) * IN_DIM + ks * 32 + quad * 8;
        bh[ks] = *(const bf16x8*)&Wh[off];
        bl[ks] = *(const bf16x8*)&Wl[off];
    }

    #pragma unroll
    for (int it = 0; it < 4; ++it) {
        int g = it * 256 + tid;      // 0..1023
        int r = g >> 4;              // 0..63
        int c8 = g & 15;             // ushort8 chunk along k
        int row = i0 + r; if (row >= N_NODES) row = N_NODES - 1;
        int ga = row * IN_DIM + c8 * 8;
        int la = r * LDK + c8 * 8;
        *(bf16x8*)&Ah[la] = *(const bf16x8*)&yh[ga];
        *(bf16x8*)&Al[la] = *(const bf16x8*)&yl[ga];
    }
    __syncthreads();

    f32x4 acc[4] = {{0.f,0.f,0.f,0.f},{0.f,0.f,0.f,0.f},{0.f,0.f,0.f,0.f},{0.f,0.f,0.f,0.f}};
    #pragma unroll
    for (int ks = 0; ks < 4; ++ks) {
        int koff = ks * 32 + quad * 8;
        #pragma unroll
        for (int mt = 0; mt < 4; ++mt) {
            bf16x8 ah = *(bf16x8*)&Ah[(mt * 16 + rl) * LDK + koff];
            bf16x8 al = *(bf16x8*)&Al[(mt * 16 + rl) * LDK + koff];
            acc[mt] = __builtin_amdgcn_mfma_f32_16x16x32_bf16(ah, bh[ks], acc[mt], 0, 0, 0);
            acc[mt] = __builtin_amdgcn_mfma_f32_16x16x32_bf16(ah, bl[ks], acc[mt], 0, 0, 0);
            acc[mt] = __builtin_amdgcn_mfma_f32_16x16x32_bf16(al, bh[ks], acc[mt], 0, 0, 0);
        }
    }

    float bv = bias[jb + n0 + rl];
    #pragma unroll
    for (int mt = 0; mt < 4; ++mt) {
        #pragma unroll
        for (int r = 0; r < 4; ++r) {
            int row = i0 + mt * 16 + quad * 4 + r;
            if (row < N_NODES) {
                float v = acc[mt][r] + bv;
                out[row * OUT_DIM + jb + n0 + rl] = fmaxf(v, 0.f);
            }
        }
    }
}

// ---------------- launch ----------------

extern "C" void kernel_launch(void* const* d_in, const int* in_sizes, int n_in,
                              void* d_out, int out_size, void* d_ws, size_t ws_size,
                              hipStream_t stream) {
    const float* x  = (const float*)d_in[0];
    const int*   ei = (const int*)d_in[1];
    const float* W  = (const float*)d_in[2];
    const float* b  = (const float*)d_in[3];
    float* out = (float*)d_out;

    char* ws = (char*)d_ws;
    int*            bcnt     = (int*)(ws + 0);                   // 782 ints (memset)
    int*            counts   = (int*)(ws + 4096);                // 50000 ints (k_degree writes)
    unsigned*       bucketed = (unsigned*)(ws + 204800);         // 782*1280 u32 (4.0 MB)
    unsigned*       yh       = (unsigned*)(ws + 4208640);        // 12.8 MB
    unsigned*       yl       = (unsigned*)(ws + 17008640);       // 12.8 MB
    unsigned short* xb       = (unsigned short*)(ws + 29808640); // 12.8 MB
    unsigned short* Wh       = (unsigned short*)(ws + 42608640); // 64 KB
    unsigned short* Wl       = (unsigned short*)(ws + 42674176); // 64 KB

    hipMemsetAsync(bcnt, 0, N_BUCKETS * sizeof(int), stream);

    k_prep<<<BINA_BLOCKS + XCONV_BLOCKS + WCONV_BLOCKS, 1024, 0, stream>>>(
        ei, bcnt, bucketed, x, xb, W, Wh, Wl);
    k_degree<<<N_BUCKETS, 256, 0, stream>>>(bcnt, bucketed, counts);
    k_aggregate<<<N_BUCKETS, 512, 0, stream>>>((const unsigned*)xb, counts, bcnt,
                                               bucketed, yh, yl);
    dim3 g(OUT_DIM / 64, (N_NODES + 63) / 64);
    k_gemm<<<g, 256, 0, stream>>>((const unsigned short*)yh, (const unsigned short*)yl,
                                  Wh, Wl, b, out);
}